// Round 3
// baseline (1012.274 us; speedup 1.0000x reference)
//
#include <hip/hip_runtime.h>
#include <hip/hip_bf16.h>
#include <math.h>

// Problem constants: B(=T)=8, C=256, H=W=64, N=4096, heads=8, d=32.
#define T_ 8
#define C_ 256
#define N_ 4096          // H*W
#define CN_ (C_ * N_)    // 1048576 elements per timestep
#define EPSB 1e-5f

// ---------------------------------------------------------------------------
// LIF: v = v + (x - v)/2 ; s = (v-1 >= 0) ; v = (1-s)*v.  Scan over t.
// Output spikes as u8 (0/1).
__global__ __launch_bounds__(256) void lif_u8(const float* __restrict__ X,
                                              unsigned char* __restrict__ S) {
    int idx = blockIdx.x * 256 + threadIdx.x;   // < CN_
    float v = 0.f;
#pragma unroll
    for (int t = 0; t < T_; t++) {
        float xt = X[(size_t)t * CN_ + idx];
        v = v + (xt - v) / 2.0f;
        unsigned char s = (v - 1.0f >= 0.f) ? 1 : 0;
        S[(size_t)t * CN_ + idx] = s;
        if (s) v = 0.f;
    }
}

// ---------------------------------------------------------------------------
// SGEMM, B operand u8 spikes: Y[t][m][n] = sum_k W[m][k] * S[t][k][n].
// 128x128 tile, BK=8, 256 threads, 8x8 micro-tile. Plain fp32 store.
__global__ __launch_bounds__(256) void gemm_s_u8(const float* __restrict__ Wm,
                                                 const unsigned char* __restrict__ S,
                                                 float* __restrict__ Y) {
    int t = blockIdx.z;
    const unsigned char* St = S + (size_t)t * CN_;
    float* Yt = Y + (size_t)t * CN_;
    int m0 = blockIdx.y * 128;
    int n0 = blockIdx.x * 128;

    __shared__ float As[8][128];
    __shared__ float Bs[8][128];

    int tid = threadIdx.x;
    int tx = tid & 15, ty = tid >> 4;

    float acc[8][8];
#pragma unroll
    for (int i = 0; i < 8; i++)
#pragma unroll
        for (int j = 0; j < 8; j++) acc[i][j] = 0.f;

    int ar = tid >> 1, ac = (tid & 1) * 4;     // A: 128 rows x 8 k
    int br = tid >> 5, bc = (tid & 31) * 4;    // B: 8 rows x 128 cols

    for (int kk = 0; kk < 256; kk += 8) {
        float4 av = *(const float4*)(&Wm[(m0 + ar) * 256 + kk + ac]);
        uchar4 bv = *(const uchar4*)(&St[(size_t)(kk + br) * N_ + n0 + bc]);
        __syncthreads();
        As[ac + 0][ar] = av.x; As[ac + 1][ar] = av.y;
        As[ac + 2][ar] = av.z; As[ac + 3][ar] = av.w;
        float4 bf = {(float)bv.x, (float)bv.y, (float)bv.z, (float)bv.w};
        *(float4*)(&Bs[br][bc]) = bf;
        __syncthreads();
#pragma unroll
        for (int k = 0; k < 8; k++) {
            float4 a0 = *(const float4*)(&As[k][ty * 4]);
            float4 a1 = *(const float4*)(&As[k][64 + ty * 4]);
            float4 b0 = *(const float4*)(&Bs[k][tx * 4]);
            float4 b1 = *(const float4*)(&Bs[k][64 + tx * 4]);
            float avv[8] = {a0.x, a0.y, a0.z, a0.w, a1.x, a1.y, a1.z, a1.w};
            float bvv[8] = {b0.x, b0.y, b0.z, b0.w, b1.x, b1.y, b1.z, b1.w};
#pragma unroll
            for (int i = 0; i < 8; i++)
#pragma unroll
                for (int j = 0; j < 8; j++) acc[i][j] += avv[i] * bvv[j];
        }
    }

#pragma unroll
    for (int half = 0; half < 2; half++) {
#pragma unroll
        for (int i = 0; i < 4; i++) {
            int row = m0 + half * 64 + ty * 4 + i;
            int ri = half * 4 + i;
            float* yrow = &Yt[(size_t)row * N_ + n0];
            float4 v0 = {acc[ri][0], acc[ri][1], acc[ri][2], acc[ri][3]};
            float4 v1 = {acc[ri][4], acc[ri][5], acc[ri][6], acc[ri][7]};
            *(float4*)(&yrow[tx * 4]) = v0;
            *(float4*)(&yrow[64 + tx * 4]) = v1;
        }
    }
}

// ---------------------------------------------------------------------------
// SGEMM, B operand fp32, fused BN(j=1) then BN(j=2) epilogue:
// y = ((y - m1)*i1 + b1 - m2)*i2 + b2.
__global__ __launch_bounds__(256) void gemm_f_bn(const float* __restrict__ Wm,
                                                 const float* __restrict__ X,
                                                 float* __restrict__ Y,
                                                 const float* __restrict__ bnp) {
    int t = blockIdx.z;
    const float* Xt = X + (size_t)t * CN_;
    float* Yt = Y + (size_t)t * CN_;
    int m0 = blockIdx.y * 128;
    int n0 = blockIdx.x * 128;

    __shared__ float As[8][128];
    __shared__ float Bs[8][128];

    int tid = threadIdx.x;
    int tx = tid & 15, ty = tid >> 4;

    float acc[8][8];
#pragma unroll
    for (int i = 0; i < 8; i++)
#pragma unroll
        for (int j = 0; j < 8; j++) acc[i][j] = 0.f;

    int ar = tid >> 1, ac = (tid & 1) * 4;
    int br = tid >> 5, bc = (tid & 31) * 4;

    for (int kk = 0; kk < 256; kk += 8) {
        float4 av = *(const float4*)(&Wm[(m0 + ar) * 256 + kk + ac]);
        float4 bv = *(const float4*)(&Xt[(size_t)(kk + br) * N_ + n0 + bc]);
        __syncthreads();
        As[ac + 0][ar] = av.x; As[ac + 1][ar] = av.y;
        As[ac + 2][ar] = av.z; As[ac + 3][ar] = av.w;
        *(float4*)(&Bs[br][bc]) = bv;
        __syncthreads();
#pragma unroll
        for (int k = 0; k < 8; k++) {
            float4 a0 = *(const float4*)(&As[k][ty * 4]);
            float4 a1 = *(const float4*)(&As[k][64 + ty * 4]);
            float4 b0 = *(const float4*)(&Bs[k][tx * 4]);
            float4 b1 = *(const float4*)(&Bs[k][64 + tx * 4]);
            float avv[8] = {a0.x, a0.y, a0.z, a0.w, a1.x, a1.y, a1.z, a1.w};
            float bvv[8] = {b0.x, b0.y, b0.z, b0.w, b1.x, b1.y, b1.z, b1.w};
#pragma unroll
            for (int i = 0; i < 8; i++)
#pragma unroll
                for (int j = 0; j < 8; j++) acc[i][j] += avv[i] * bvv[j];
        }
    }

#pragma unroll
    for (int half = 0; half < 2; half++) {
#pragma unroll
        for (int i = 0; i < 4; i++) {
            int row = m0 + half * 64 + ty * 4 + i;
            int ri = half * 4 + i;
            // bn params layout: bnp[j*4*256 + p*256 + c], p in {w,b,m,v}
            float i1 = bnp[1024 + row] / sqrtf(bnp[1024 + 768 + row] + EPSB);
            float b1 = bnp[1024 + 256 + row], m1 = bnp[1024 + 512 + row];
            float i2 = bnp[2048 + row] / sqrtf(bnp[2048 + 768 + row] + EPSB);
            float b2 = bnp[2048 + 256 + row], m2 = bnp[2048 + 512 + row];
            float r[8];
#pragma unroll
            for (int j = 0; j < 8; j++)
                r[j] = ((acc[ri][j] - m1) * i1 + b1 - m2) * i2 + b2;
            float* yrow = &Yt[(size_t)row * N_ + n0];
            float4 v0 = {r[0], r[1], r[2], r[3]};
            float4 v1 = {r[4], r[5], r[6], r[7]};
            *(float4*)(&yrow[tx * 4]) = v0;
            *(float4*)(&yrow[64 + tx * 4]) = v1;
        }
    }
}

// ---------------------------------------------------------------------------
// Fused BN1 + pad(border=bn1(0)) + 3x3 depthwise (cross-correlation, VALID).
__global__ __launch_bounds__(256) void dw_bn_pad(const float* __restrict__ Yin,
                                                 const float* __restrict__ dw,
                                                 const float* __restrict__ bnp,
                                                 float* __restrict__ Z) {
    int t = blockIdx.z, c = blockIdx.y;
    int x = threadIdx.x & 63;
    int y = blockIdx.x * 4 + (threadIdx.x >> 6);
    const float* Yc = Yin + (size_t)t * CN_ + (size_t)c * N_;

    float w = bnp[c], b = bnp[256 + c], m = bnp[512 + c], var = bnp[768 + c];
    float sq = sqrtf(var + EPSB);
    float inv = w / sq;
    float pad = b - (m * w) / sq;   // matches ref: b - m*w/sqrt(v+eps)

    float accum = 0.f;
#pragma unroll
    for (int dy = 0; dy < 3; dy++) {
        int yy = y + dy - 1;
#pragma unroll
        for (int dx = 0; dx < 3; dx++) {
            int xx = x + dx - 1;
            float val;
            if (yy < 0 || yy >= 64 || xx < 0 || xx >= 64) val = pad;
            else val = (Yc[yy * 64 + xx] - m) * inv + b;
            accum += dw[c * 9 + dy * 3 + dx] * val;
        }
    }
    Z[(size_t)t * CN_ + (size_t)c * N_ + y * 64 + x] = accum;
}

// ---------------------------------------------------------------------------
// kv[t,h,d,e] = sum_n k[t, h*32+d, n] * v[t, h*32+e, n]  (exact integer counts)
__global__ __launch_bounds__(256) void attn_kv_u8(const unsigned char* __restrict__ k,
                                                  const unsigned char* __restrict__ v,
                                                  float* __restrict__ kvbuf) {
    int th = blockIdx.x;                 // t*8+h
    const unsigned char* kb = k + (size_t)(th / 8) * CN_ + (size_t)(th % 8) * 32 * N_;
    const unsigned char* vb = v + (size_t)(th / 8) * CN_ + (size_t)(th % 8) * 32 * N_;
    __shared__ float ks[32][65];
    __shared__ float vs[32][65];
    int tid = threadIdx.x;
    int d = tid >> 3;
    int e0 = (tid & 7) * 4;
    float a0 = 0.f, a1 = 0.f, a2 = 0.f, a3 = 0.f;
    for (int n0 = 0; n0 < N_; n0 += 64) {
        for (int i = tid * 4; i < 2048; i += 1024) {
            int r = i >> 6, cc = i & 63;
            uchar4 kq = *(const uchar4*)(&kb[(size_t)r * N_ + n0 + cc]);
            uchar4 vq = *(const uchar4*)(&vb[(size_t)r * N_ + n0 + cc]);
            ks[r][cc + 0] = (float)kq.x; ks[r][cc + 1] = (float)kq.y;
            ks[r][cc + 2] = (float)kq.z; ks[r][cc + 3] = (float)kq.w;
            vs[r][cc + 0] = (float)vq.x; vs[r][cc + 1] = (float)vq.y;
            vs[r][cc + 2] = (float)vq.z; vs[r][cc + 3] = (float)vq.w;
        }
        __syncthreads();
#pragma unroll 8
        for (int n = 0; n < 64; n++) {
            float kd = ks[d][n];
            a0 += kd * vs[e0 + 0][n];
            a1 += kd * vs[e0 + 1][n];
            a2 += kd * vs[e0 + 2][n];
            a3 += kd * vs[e0 + 3][n];
        }
        __syncthreads();
    }
    float* out = kvbuf + (size_t)th * 1024 + d * 32 + e0;
    out[0] = a0; out[1] = a1; out[2] = a2; out[3] = a3;
}

// ---------------------------------------------------------------------------
// o[t, h*32+e, n] = scale * sum_d q[t, h*32+d, n] * kv[t,h,d,e]
__global__ __launch_bounds__(256) void attn_o_u8(const unsigned char* __restrict__ q,
                                                 const float* __restrict__ kvbuf,
                                                 float* __restrict__ o) {
    int t = blockIdx.z, h = blockIdx.y;
    int n = blockIdx.x * 1024 + threadIdx.x * 4;
    __shared__ float kvs[1024];
    const float* kv = kvbuf + (size_t)(t * 8 + h) * 1024;
    for (int i = threadIdx.x; i < 1024; i += 256) kvs[i] = kv[i];
    __syncthreads();
    const unsigned char* qb = q + (size_t)t * CN_ + (size_t)h * 32 * N_ + n;
    float* ob = o + (size_t)t * CN_ + (size_t)h * 32 * N_ + n;
    const float scale = 0.17677669529663687f;  // 32^-0.5
#pragma unroll
    for (int eg = 0; eg < 2; eg++) {
        float acc[16][4];
#pragma unroll
        for (int e = 0; e < 16; e++)
#pragma unroll
            for (int j = 0; j < 4; j++) acc[e][j] = 0.f;
        for (int d = 0; d < 32; d++) {
            uchar4 qu = *(const uchar4*)(&qb[(size_t)d * N_]);
            float4 qv = {(float)qu.x, (float)qu.y, (float)qu.z, (float)qu.w};
#pragma unroll
            for (int e = 0; e < 16; e++) {
                float kvv = kvs[d * 32 + eg * 16 + e];
                acc[e][0] += qv.x * kvv;
                acc[e][1] += qv.y * kvv;
                acc[e][2] += qv.z * kvv;
                acc[e][3] += qv.w * kvv;
            }
        }
#pragma unroll
        for (int e = 0; e < 16; e++) {
            float4 ov = {acc[e][0] * scale, acc[e][1] * scale,
                         acc[e][2] * scale, acc[e][3] * scale};
            *(float4*)(&ob[(size_t)(eg * 16 + e) * N_]) = ov;
        }
    }
}

// ---------------------------------------------------------------------------
extern "C" void kernel_launch(void* const* d_in, const int* in_sizes, int n_in,
                              void* d_out, int out_size, void* d_ws, size_t ws_size,
                              hipStream_t stream) {
    const float* x = (const float*)d_in[0];
    const float* q_w1 = (const float*)d_in[1];
    const float* q_dw = (const float*)d_in[2];
    const float* q_pw = (const float*)d_in[3];
    const float* q_bn = (const float*)d_in[4];
    const float* k_w1 = (const float*)d_in[5];
    const float* k_dw = (const float*)d_in[6];
    const float* k_pw = (const float*)d_in[7];
    const float* k_bn = (const float*)d_in[8];
    const float* v_w1 = (const float*)d_in[9];
    const float* v_dw = (const float*)d_in[10];
    const float* v_pw = (const float*)d_in[11];
    const float* v_bn = (const float*)d_in[12];
    const float* p_w1 = (const float*)d_in[13];
    const float* p_dw = (const float*)d_in[14];
    const float* p_pw = (const float*)d_in[15];
    const float* p_bn = (const float*)d_in[16];

    const size_t SZ = (size_t)T_ * CN_;  // 8,388,608 elements per tensor
    float* out = (float*)d_out;          // doubles as fp32 scratch (ping)
    float* S0 = (float*)d_ws;            // fp32 scratch (pong), 33.5 MB
    float* bufKV = S0 + SZ;              // 65,536 floats
    unsigned char* spk = (unsigned char*)(bufKV + 65536);
    unsigned char* xs = spk;             // reused for o-spikes after v branch
    unsigned char* sq = spk + SZ;
    unsigned char* sk = spk + 2 * SZ;
    unsigned char* sv = spk + 3 * SZ;
    // total ws usage: 33.5MB + 0.26MB + 4*8.39MB = ~64.3 MB

    dim3 gLif(CN_ / 256), bLif(256);
    dim3 gGemm(N_ / 128, C_ / 128, T_), bGemm(256);
    dim3 gDw(16, C_, T_), bDw(256);

    // xs = lif(x)
    lif_u8<<<gLif, bLif, 0, stream>>>(x, xs);

    // q branch: gemm1 -> out, dw -> S0, gemm2 -> out, lif -> sq
    gemm_s_u8<<<gGemm, bGemm, 0, stream>>>(q_w1, xs, out);
    dw_bn_pad<<<gDw, bDw, 0, stream>>>(out, q_dw, q_bn, S0);
    gemm_f_bn<<<gGemm, bGemm, 0, stream>>>(q_pw, S0, out, q_bn);
    lif_u8<<<gLif, bLif, 0, stream>>>(out, sq);

    // k branch
    gemm_s_u8<<<gGemm, bGemm, 0, stream>>>(k_w1, xs, out);
    dw_bn_pad<<<gDw, bDw, 0, stream>>>(out, k_dw, k_bn, S0);
    gemm_f_bn<<<gGemm, bGemm, 0, stream>>>(k_pw, S0, out, k_bn);
    lif_u8<<<gLif, bLif, 0, stream>>>(out, sk);

    // v branch
    gemm_s_u8<<<gGemm, bGemm, 0, stream>>>(v_w1, xs, out);
    dw_bn_pad<<<gDw, bDw, 0, stream>>>(out, v_dw, v_bn, S0);
    gemm_f_bn<<<gGemm, bGemm, 0, stream>>>(v_pw, S0, out, v_bn);
    lif_u8<<<gLif, bLif, 0, stream>>>(out, sv);

    // attention (exact integer arithmetic in fp32); xs is dead -> o spikes
    attn_kv_u8<<<dim3(64), dim3(256), 0, stream>>>(sk, sv, bufKV);
    attn_o_u8<<<dim3(4, 8, 8), dim3(256), 0, stream>>>(sq, bufKV, S0);
    lif_u8<<<gLif, bLif, 0, stream>>>(S0, xs);

    // p branch -> d_out
    gemm_s_u8<<<gGemm, bGemm, 0, stream>>>(p_w1, xs, out);
    dw_bn_pad<<<gDw, bDw, 0, stream>>>(out, p_dw, p_bn, S0);
    gemm_f_bn<<<gGemm, bGemm, 0, stream>>>(p_pw, S0, out, p_bn);
}

// Round 4
// 831.117 us; speedup vs baseline: 1.2180x; 1.2180x over previous
//
#include <hip/hip_runtime.h>
#include <hip/hip_bf16.h>
#include <math.h>

// Problem constants: B(=T)=8, C=256, H=W=64, N=4096, heads=8, d=32.
#define T_ 8
#define C_ 256
#define N_ 4096          // H*W
#define CN_ (C_ * N_)    // 1048576 elements per timestep
#define EPSB 1e-5f

typedef unsigned long long u64;

// ---------------------------------------------------------------------------
// LIF: v = v + (x - v)/2 ; s = (v-1 >= 0) ; v = (1-s)*v.  Scan over t.
// Output spikes as u8 (0/1).
__global__ __launch_bounds__(256) void lif_u8(const float* __restrict__ X,
                                              unsigned char* __restrict__ S) {
    int idx = blockIdx.x * 256 + threadIdx.x;   // < CN_
    float v = 0.f;
#pragma unroll
    for (int t = 0; t < T_; t++) {
        float xt = X[(size_t)t * CN_ + idx];
        v = v + (xt - v) / 2.0f;
        unsigned char s = (v - 1.0f >= 0.f) ? 1 : 0;
        S[(size_t)t * CN_ + idx] = s;
        if (s) v = 0.f;
    }
}

// LIF variant writing only bitpacked spikes (bit l of word w = n = w*64+l within
// the channel row; layout BP[t][c][64 words], i.e. global word idx = idx>>6).
__global__ __launch_bounds__(256) void lif_bp(const float* __restrict__ X,
                                              u64* __restrict__ BP) {
    int idx = blockIdx.x * 256 + threadIdx.x;   // < CN_
    int lane = threadIdx.x & 63;
    float v = 0.f;
#pragma unroll
    for (int t = 0; t < T_; t++) {
        float xt = X[(size_t)t * CN_ + idx];
        v = v + (xt - v) / 2.0f;
        int s = (v - 1.0f >= 0.f) ? 1 : 0;
        u64 mask = __ballot(s);
        if (lane == 0) BP[((size_t)t * CN_ + idx) >> 6] = mask;
        if (s) v = 0.f;
    }
}

// ---------------------------------------------------------------------------
// SGEMM, B operand u8 spikes: Y[t][m][n] = sum_k W[m][k] * S[t][k][n].
// 128x128 tile, BK=8, 256 threads, 8x8 micro-tile. Plain fp32 store.
__global__ __launch_bounds__(256) void gemm_s_u8(const float* __restrict__ Wm,
                                                 const unsigned char* __restrict__ S,
                                                 float* __restrict__ Y) {
    int t = blockIdx.z;
    const unsigned char* St = S + (size_t)t * CN_;
    float* Yt = Y + (size_t)t * CN_;
    int m0 = blockIdx.y * 128;
    int n0 = blockIdx.x * 128;

    __shared__ float As[8][128];
    __shared__ float Bs[8][128];

    int tid = threadIdx.x;
    int tx = tid & 15, ty = tid >> 4;

    float acc[8][8];
#pragma unroll
    for (int i = 0; i < 8; i++)
#pragma unroll
        for (int j = 0; j < 8; j++) acc[i][j] = 0.f;

    int ar = tid >> 1, ac = (tid & 1) * 4;     // A: 128 rows x 8 k
    int br = tid >> 5, bc = (tid & 31) * 4;    // B: 8 rows x 128 cols

    for (int kk = 0; kk < 256; kk += 8) {
        float4 av = *(const float4*)(&Wm[(m0 + ar) * 256 + kk + ac]);
        uchar4 bv = *(const uchar4*)(&St[(size_t)(kk + br) * N_ + n0 + bc]);
        __syncthreads();
        As[ac + 0][ar] = av.x; As[ac + 1][ar] = av.y;
        As[ac + 2][ar] = av.z; As[ac + 3][ar] = av.w;
        float4 bf = {(float)bv.x, (float)bv.y, (float)bv.z, (float)bv.w};
        *(float4*)(&Bs[br][bc]) = bf;
        __syncthreads();
#pragma unroll
        for (int k = 0; k < 8; k++) {
            float4 a0 = *(const float4*)(&As[k][ty * 4]);
            float4 a1 = *(const float4*)(&As[k][64 + ty * 4]);
            float4 b0 = *(const float4*)(&Bs[k][tx * 4]);
            float4 b1 = *(const float4*)(&Bs[k][64 + tx * 4]);
            float avv[8] = {a0.x, a0.y, a0.z, a0.w, a1.x, a1.y, a1.z, a1.w};
            float bvv[8] = {b0.x, b0.y, b0.z, b0.w, b1.x, b1.y, b1.z, b1.w};
#pragma unroll
            for (int i = 0; i < 8; i++)
#pragma unroll
                for (int j = 0; j < 8; j++) acc[i][j] += avv[i] * bvv[j];
        }
    }

#pragma unroll
    for (int half = 0; half < 2; half++) {
#pragma unroll
        for (int i = 0; i < 4; i++) {
            int row = m0 + half * 64 + ty * 4 + i;
            int ri = half * 4 + i;
            float* yrow = &Yt[(size_t)row * N_ + n0];
            float4 v0 = {acc[ri][0], acc[ri][1], acc[ri][2], acc[ri][3]};
            float4 v1 = {acc[ri][4], acc[ri][5], acc[ri][6], acc[ri][7]};
            *(float4*)(&yrow[tx * 4]) = v0;
            *(float4*)(&yrow[64 + tx * 4]) = v1;
        }
    }
}

// ---------------------------------------------------------------------------
// SGEMM, B operand fp32, fused BN(j=1) then BN(j=2) epilogue:
// y = ((y - m1)*i1 + b1 - m2)*i2 + b2.
__global__ __launch_bounds__(256) void gemm_f_bn(const float* __restrict__ Wm,
                                                 const float* __restrict__ X,
                                                 float* __restrict__ Y,
                                                 const float* __restrict__ bnp) {
    int t = blockIdx.z;
    const float* Xt = X + (size_t)t * CN_;
    float* Yt = Y + (size_t)t * CN_;
    int m0 = blockIdx.y * 128;
    int n0 = blockIdx.x * 128;

    __shared__ float As[8][128];
    __shared__ float Bs[8][128];

    int tid = threadIdx.x;
    int tx = tid & 15, ty = tid >> 4;

    float acc[8][8];
#pragma unroll
    for (int i = 0; i < 8; i++)
#pragma unroll
        for (int j = 0; j < 8; j++) acc[i][j] = 0.f;

    int ar = tid >> 1, ac = (tid & 1) * 4;
    int br = tid >> 5, bc = (tid & 31) * 4;

    for (int kk = 0; kk < 256; kk += 8) {
        float4 av = *(const float4*)(&Wm[(m0 + ar) * 256 + kk + ac]);
        float4 bv = *(const float4*)(&Xt[(size_t)(kk + br) * N_ + n0 + bc]);
        __syncthreads();
        As[ac + 0][ar] = av.x; As[ac + 1][ar] = av.y;
        As[ac + 2][ar] = av.z; As[ac + 3][ar] = av.w;
        *(float4*)(&Bs[br][bc]) = bv;
        __syncthreads();
#pragma unroll
        for (int k = 0; k < 8; k++) {
            float4 a0 = *(const float4*)(&As[k][ty * 4]);
            float4 a1 = *(const float4*)(&As[k][64 + ty * 4]);
            float4 b0 = *(const float4*)(&Bs[k][tx * 4]);
            float4 b1 = *(const float4*)(&Bs[k][64 + tx * 4]);
            float avv[8] = {a0.x, a0.y, a0.z, a0.w, a1.x, a1.y, a1.z, a1.w};
            float bvv[8] = {b0.x, b0.y, b0.z, b0.w, b1.x, b1.y, b1.z, b1.w};
#pragma unroll
            for (int i = 0; i < 8; i++)
#pragma unroll
                for (int j = 0; j < 8; j++) acc[i][j] += avv[i] * bvv[j];
        }
    }

#pragma unroll
    for (int half = 0; half < 2; half++) {
#pragma unroll
        for (int i = 0; i < 4; i++) {
            int row = m0 + half * 64 + ty * 4 + i;
            int ri = half * 4 + i;
            // bn params layout: bnp[j*4*256 + p*256 + c], p in {w,b,m,v}
            float i1 = bnp[1024 + row] / sqrtf(bnp[1024 + 768 + row] + EPSB);
            float b1 = bnp[1024 + 256 + row], m1 = bnp[1024 + 512 + row];
            float i2 = bnp[2048 + row] / sqrtf(bnp[2048 + 768 + row] + EPSB);
            float b2 = bnp[2048 + 256 + row], m2 = bnp[2048 + 512 + row];
            float r[8];
#pragma unroll
            for (int j = 0; j < 8; j++)
                r[j] = ((acc[ri][j] - m1) * i1 + b1 - m2) * i2 + b2;
            float* yrow = &Yt[(size_t)row * N_ + n0];
            float4 v0 = {r[0], r[1], r[2], r[3]};
            float4 v1 = {r[4], r[5], r[6], r[7]};
            *(float4*)(&yrow[tx * 4]) = v0;
            *(float4*)(&yrow[64 + tx * 4]) = v1;
        }
    }
}

// ---------------------------------------------------------------------------
// Fused BN1 + pad(border=bn1(0)) + 3x3 depthwise (cross-correlation, VALID).
__global__ __launch_bounds__(256) void dw_bn_pad(const float* __restrict__ Yin,
                                                 const float* __restrict__ dw,
                                                 const float* __restrict__ bnp,
                                                 float* __restrict__ Z) {
    int t = blockIdx.z, c = blockIdx.y;
    int x = threadIdx.x & 63;
    int y = blockIdx.x * 4 + (threadIdx.x >> 6);
    const float* Yc = Yin + (size_t)t * CN_ + (size_t)c * N_;

    float w = bnp[c], b = bnp[256 + c], m = bnp[512 + c], var = bnp[768 + c];
    float sq = sqrtf(var + EPSB);
    float inv = w / sq;
    float pad = b - (m * w) / sq;   // matches ref: b - m*w/sqrt(v+eps)

    float accum = 0.f;
#pragma unroll
    for (int dy = 0; dy < 3; dy++) {
        int yy = y + dy - 1;
#pragma unroll
        for (int dx = 0; dx < 3; dx++) {
            int xx = x + dx - 1;
            float val;
            if (yy < 0 || yy >= 64 || xx < 0 || xx >= 64) val = pad;
            else val = (Yc[yy * 64 + xx] - m) * inv + b;
            accum += dw[c * 9 + dy * 3 + dx] * val;
        }
    }
    Z[(size_t)t * CN_ + (size_t)c * N_ + y * 64 + x] = accum;
}

// ---------------------------------------------------------------------------
// Bitpacked kv: kv[t,h,d,e] = sum_w popcount(Kbp[h*32+d][w] & Vbp[h*32+e][w]).
// One block per (t,h), 1024 threads = one per (d,e) pair. LDS padded [32][65]
// so the stride-64-word column walk hits 16 banks (2-way = free).
__global__ __launch_bounds__(1024) void attn_kv_bp(const u64* __restrict__ Kbp,
                                                   const u64* __restrict__ Vbp,
                                                   float* __restrict__ kvbuf) {
    int th = blockIdx.x;                 // t*8+h
    int t = th >> 3, h = th & 7;
    const u64* kb = Kbp + ((size_t)t * C_ + h * 32) * 64;
    const u64* vb = Vbp + ((size_t)t * C_ + h * 32) * 64;
    __shared__ u64 ks[32][65];
    __shared__ u64 vs[32][65];
    int tid = threadIdx.x;
    {
        int r = tid >> 5, w2 = (tid & 31) * 2;
        ks[r][w2] = kb[r * 64 + w2];     ks[r][w2 + 1] = kb[r * 64 + w2 + 1];
        vs[r][w2] = vb[r * 64 + w2];     vs[r][w2 + 1] = vb[r * 64 + w2 + 1];
    }
    __syncthreads();
    int d = tid >> 5, e = tid & 31;
    int cnt = 0;
#pragma unroll
    for (int w = 0; w < 64; w++)
        cnt += __popcll(ks[d][w] & vs[e][w]);
    kvbuf[(size_t)th * 1024 + d * 32 + e] = (float)cnt;
}

// ---------------------------------------------------------------------------
// o[t, h*32+e, n] = scale * sum_d q[t, h*32+d, n] * kv[t,h,d,e]
__global__ __launch_bounds__(256) void attn_o_u8(const unsigned char* __restrict__ q,
                                                 const float* __restrict__ kvbuf,
                                                 float* __restrict__ o) {
    int t = blockIdx.z, h = blockIdx.y;
    int n = blockIdx.x * 1024 + threadIdx.x * 4;
    __shared__ float kvs[1024];
    const float* kv = kvbuf + (size_t)(t * 8 + h) * 1024;
    for (int i = threadIdx.x; i < 1024; i += 256) kvs[i] = kv[i];
    __syncthreads();
    const unsigned char* qb = q + (size_t)t * CN_ + (size_t)h * 32 * N_ + n;
    float* ob = o + (size_t)t * CN_ + (size_t)h * 32 * N_ + n;
    const float scale = 0.17677669529663687f;  // 32^-0.5
#pragma unroll
    for (int eg = 0; eg < 2; eg++) {
        float acc[16][4];
#pragma unroll
        for (int e = 0; e < 16; e++)
#pragma unroll
            for (int j = 0; j < 4; j++) acc[e][j] = 0.f;
        for (int d = 0; d < 32; d++) {
            uchar4 qu = *(const uchar4*)(&qb[(size_t)d * N_]);
            float4 qv = {(float)qu.x, (float)qu.y, (float)qu.z, (float)qu.w};
#pragma unroll
            for (int e = 0; e < 16; e++) {
                float kvv = kvs[d * 32 + eg * 16 + e];
                acc[e][0] += qv.x * kvv;
                acc[e][1] += qv.y * kvv;
                acc[e][2] += qv.z * kvv;
                acc[e][3] += qv.w * kvv;
            }
        }
#pragma unroll
        for (int e = 0; e < 16; e++) {
            float4 ov = {acc[e][0] * scale, acc[e][1] * scale,
                         acc[e][2] * scale, acc[e][3] * scale};
            *(float4*)(&ob[(size_t)(eg * 16 + e) * N_]) = ov;
        }
    }
}

// ---------------------------------------------------------------------------
extern "C" void kernel_launch(void* const* d_in, const int* in_sizes, int n_in,
                              void* d_out, int out_size, void* d_ws, size_t ws_size,
                              hipStream_t stream) {
    const float* x = (const float*)d_in[0];
    const float* q_w1 = (const float*)d_in[1];
    const float* q_dw = (const float*)d_in[2];
    const float* q_pw = (const float*)d_in[3];
    const float* q_bn = (const float*)d_in[4];
    const float* k_w1 = (const float*)d_in[5];
    const float* k_dw = (const float*)d_in[6];
    const float* k_pw = (const float*)d_in[7];
    const float* k_bn = (const float*)d_in[8];
    const float* v_w1 = (const float*)d_in[9];
    const float* v_dw = (const float*)d_in[10];
    const float* v_pw = (const float*)d_in[11];
    const float* v_bn = (const float*)d_in[12];
    const float* p_w1 = (const float*)d_in[13];
    const float* p_dw = (const float*)d_in[14];
    const float* p_pw = (const float*)d_in[15];
    const float* p_bn = (const float*)d_in[16];

    const size_t SZ = (size_t)T_ * CN_;  // 8,388,608 elements per tensor
    float* out = (float*)d_out;          // doubles as fp32 scratch (ping)
    float* S0 = (float*)d_ws;            // fp32 scratch (pong), 33.5 MB
    float* bufKV = S0 + SZ;              // 65,536 floats
    unsigned char* xs = (unsigned char*)(bufKV + 65536);  // u8 spikes (x / o reuse)
    unsigned char* sq = xs + SZ;                          // u8 spikes (q)
    u64* kbp = (u64*)(sq + SZ);          // bitpacked k spikes, 131072 u64
    u64* vbp = kbp + (SZ >> 6);          // bitpacked v spikes
    // total ws usage: 33.5 + 0.26 + 2*8.39 + 2*1.05 = ~52.7 MB

    dim3 gLif(CN_ / 256), bLif(256);
    dim3 gGemm(N_ / 128, C_ / 128, T_), bGemm(256);
    dim3 gDw(16, C_, T_), bDw(256);

    // xs = lif(x)
    lif_u8<<<gLif, bLif, 0, stream>>>(x, xs);

    // q branch: gemm1 -> out, dw -> S0, gemm2 -> out, lif -> sq (u8)
    gemm_s_u8<<<gGemm, bGemm, 0, stream>>>(q_w1, xs, out);
    dw_bn_pad<<<gDw, bDw, 0, stream>>>(out, q_dw, q_bn, S0);
    gemm_f_bn<<<gGemm, bGemm, 0, stream>>>(q_pw, S0, out, q_bn);
    lif_u8<<<gLif, bLif, 0, stream>>>(out, sq);

    // k branch -> bitpacked spikes only
    gemm_s_u8<<<gGemm, bGemm, 0, stream>>>(k_w1, xs, out);
    dw_bn_pad<<<gDw, bDw, 0, stream>>>(out, k_dw, k_bn, S0);
    gemm_f_bn<<<gGemm, bGemm, 0, stream>>>(k_pw, S0, out, k_bn);
    lif_bp<<<gLif, bLif, 0, stream>>>(out, kbp);

    // v branch -> bitpacked spikes only
    gemm_s_u8<<<gGemm, bGemm, 0, stream>>>(v_w1, xs, out);
    dw_bn_pad<<<gDw, bDw, 0, stream>>>(out, v_dw, v_bn, S0);
    gemm_f_bn<<<gGemm, bGemm, 0, stream>>>(v_pw, S0, out, v_bn);
    lif_bp<<<gLif, bLif, 0, stream>>>(out, vbp);

    // attention: bitpacked popcount kv (exact), then o = q . kv
    attn_kv_bp<<<dim3(64), dim3(1024), 0, stream>>>(kbp, vbp, bufKV);
    attn_o_u8<<<dim3(4, 8, 8), dim3(256), 0, stream>>>(sq, bufKV, S0);
    lif_u8<<<gLif, bLif, 0, stream>>>(S0, xs);   // xs reused for o spikes

    // p branch -> d_out
    gemm_s_u8<<<gGemm, bGemm, 0, stream>>>(p_w1, xs, out);
    dw_bn_pad<<<gDw, bDw, 0, stream>>>(out, p_dw, p_bn, S0);
    gemm_f_bn<<<gGemm, bGemm, 0, stream>>>(p_pw, S0, out, p_bn);
}

// Round 5
// 740.532 us; speedup vs baseline: 1.3670x; 1.1223x over previous
//
#include <hip/hip_runtime.h>
#include <hip/hip_bf16.h>
#include <math.h>

// Problem constants: B(=T)=8, C=256, H=W=64, N=4096, heads=8, d=32.
#define T_ 8
#define C_ 256
#define N_ 4096          // H*W
#define CN_ (C_ * N_)    // 1048576 elements per timestep
#define EPSB 1e-5f

typedef unsigned long long u64;
typedef short bf16x8 __attribute__((ext_vector_type(8)));
typedef float f32x4 __attribute__((ext_vector_type(4)));

static __device__ __forceinline__ unsigned short f2bf(float f) {
    __hip_bfloat16 h = __float2bfloat16(f);   // RTNE
    return *(unsigned short*)&h;
}
static __device__ __forceinline__ float bf2f(unsigned short u) {
    unsigned int x = (unsigned int)u << 16;   // exact widen
    return *(float*)&x;
}

// ---------------------------------------------------------------------------
// LIF scan over t: u8 spikes.
__global__ __launch_bounds__(256) void lif_u8(const float* __restrict__ X,
                                              unsigned char* __restrict__ S) {
    int idx = blockIdx.x * 256 + threadIdx.x;
    float v = 0.f;
#pragma unroll
    for (int t = 0; t < T_; t++) {
        float xt = X[(size_t)t * CN_ + idx];
        v = v + (xt - v) / 2.0f;
        unsigned char s = (v - 1.0f >= 0.f) ? 1 : 0;
        S[(size_t)t * CN_ + idx] = s;
        if (s) v = 0.f;
    }
}

// LIF writing bitpacked spikes (bit l of word w = n = w*64+l).
__global__ __launch_bounds__(256) void lif_bp(const float* __restrict__ X,
                                              u64* __restrict__ BP) {
    int idx = blockIdx.x * 256 + threadIdx.x;
    int lane = threadIdx.x & 63;
    float v = 0.f;
#pragma unroll
    for (int t = 0; t < T_; t++) {
        float xt = X[(size_t)t * CN_ + idx];
        v = v + (xt - v) / 2.0f;
        int s = (v - 1.0f >= 0.f) ? 1 : 0;
        u64 mask = __ballot(s);
        if (lane == 0) BP[((size_t)t * CN_ + idx) >> 6] = mask;
        if (s) v = 0.f;
    }
}

// ---------------------------------------------------------------------------
// Exact 3-way bf16 split of the eight 256x256 weight matrices.
// out layout: [mat 8][split 3][256*256] bf16 bits.
struct WPtrs { const float* w[8]; };
__global__ __launch_bounds__(256) void split_w(WPtrs p, unsigned short* __restrict__ out) {
    int mat = blockIdx.y;
    int idx = blockIdx.x * 256 + threadIdx.x;   // < 65536
    float w = p.w[mat][idx];
    unsigned short h1 = f2bf(w);
    float f1 = bf2f(h1);
    unsigned short h2 = f2bf(w - f1);
    float f2v = bf2f(h2);
    unsigned short h3 = f2bf(w - f1 - f2v);     // exact: 8+8+8 bits cover fp32
    size_t base = (size_t)mat * 3 * 65536 + idx;
    out[base] = h1;
    out[base + 65536] = h2;
    out[base + 2 * 65536] = h3;
}

// ---------------------------------------------------------------------------
// MFMA GEMM, B = u8 spikes (exact in bf16): Y[t][m][n] = sum_k W[m][k]*S[t][k][n].
// 128x128 tile, 4 waves 2x2, BK=32, A = 3 exact bf16 splits from global.
__global__ __launch_bounds__(256) void gemm_s_mfma(const unsigned short* __restrict__ Wsp,
                                                   const unsigned char* __restrict__ S,
                                                   float* __restrict__ Y) {
    int t = blockIdx.z;
    const unsigned char* St = S + (size_t)t * CN_;
    float* Yt = Y + (size_t)t * CN_;
    int m0 = blockIdx.y * 128, n0 = blockIdx.x * 128;
    int tid = threadIdx.x;
    int lane = tid & 63, wave = tid >> 6;
    int wm = wave >> 1, wn = wave & 1;
    int lcol = lane & 15, quad = lane >> 4;

    __shared__ unsigned short Bs[128][32];   // [n][k], k contiguous

    f32x4 acc[4][4];
#pragma unroll
    for (int i = 0; i < 4; i++)
#pragma unroll
        for (int j = 0; j < 4; j++) acc[i][j] = (f32x4){0.f, 0.f, 0.f, 0.f};

    int rp = tid >> 4;          // k-pair 0..15 -> rows 2rp, 2rp+1
    int c0 = (tid & 15) * 8;    // n cols c0..c0+7

    for (int kk = 0; kk < 256; kk += 32) {
        const unsigned char* r0p = &St[(size_t)(kk + 2 * rp) * N_ + n0 + c0];
        u64 u0 = *(const u64*)r0p;
        u64 u1 = *(const u64*)(r0p + N_);
        __syncthreads();
#pragma unroll
        for (int j = 0; j < 8; j++) {
            unsigned int lo = (unsigned int)((u0 >> (8 * j)) & 1u) * 0x3F80u;
            unsigned int hi = (unsigned int)((u1 >> (8 * j)) & 1u) * 0x3F80u;
            *(unsigned int*)&Bs[c0 + j][2 * rp] = lo | (hi << 16);
        }
        __syncthreads();

        bf16x8 bfr[4];
#pragma unroll
        for (int nt = 0; nt < 4; nt++)
            bfr[nt] = *(const bf16x8*)&Bs[wn * 64 + nt * 16 + lcol][quad * 8];

#pragma unroll
        for (int s = 0; s < 3; s++) {
            const unsigned short* Ws = Wsp + (size_t)s * 65536;
#pragma unroll
            for (int mt = 0; mt < 4; mt++) {
                int m = m0 + wm * 64 + mt * 16 + lcol;
                bf16x8 afr = *(const bf16x8*)&Ws[m * 256 + kk + quad * 8];
#pragma unroll
                for (int nt = 0; nt < 4; nt++)
                    acc[mt][nt] = __builtin_amdgcn_mfma_f32_16x16x32_bf16(
                        afr, bfr[nt], acc[mt][nt], 0, 0, 0);
            }
        }
    }

#pragma unroll
    for (int mt = 0; mt < 4; mt++)
#pragma unroll
        for (int i = 0; i < 4; i++) {
            int row = m0 + wm * 64 + mt * 16 + quad * 4 + i;
            float* yr = &Yt[(size_t)row * N_ + n0 + wn * 64 + lcol];
#pragma unroll
            for (int nt = 0; nt < 4; nt++) yr[nt * 16] = acc[mt][nt][i];
        }
}

// ---------------------------------------------------------------------------
// MFMA GEMM, B = fp32 (2-way bf16 split), fused BN(j=1)->BN(j=2) epilogue.
// Passes: a1b1, a1b2, a2b1, a2b2, a3b1 (terms >= 2^-18 significance).
__global__ __launch_bounds__(256) void gemm_f_mfma(const unsigned short* __restrict__ Wsp,
                                                   const float* __restrict__ X,
                                                   float* __restrict__ Y,
                                                   const float* __restrict__ bnp) {
    int t = blockIdx.z;
    const float* Xt = X + (size_t)t * CN_;
    float* Yt = Y + (size_t)t * CN_;
    int m0 = blockIdx.y * 128, n0 = blockIdx.x * 128;
    int tid = threadIdx.x;
    int lane = tid & 63, wave = tid >> 6;
    int wm = wave >> 1, wn = wave & 1;
    int lcol = lane & 15, quad = lane >> 4;

    __shared__ unsigned short Bh[128][32];
    __shared__ unsigned short Bl[128][32];

    f32x4 acc[4][4];
#pragma unroll
    for (int i = 0; i < 4; i++)
#pragma unroll
        for (int j = 0; j < 4; j++) acc[i][j] = (f32x4){0.f, 0.f, 0.f, 0.f};

    int rp = tid >> 4;
    int c0 = (tid & 15) * 8;

    for (int kk = 0; kk < 256; kk += 32) {
        const float* r0p = &Xt[(size_t)(kk + 2 * rp) * N_ + n0 + c0];
        float4 x00 = *(const float4*)r0p;
        float4 x01 = *(const float4*)(r0p + 4);
        float4 x10 = *(const float4*)(r0p + N_);
        float4 x11 = *(const float4*)(r0p + N_ + 4);
        __syncthreads();
        float e0[8] = {x00.x, x00.y, x00.z, x00.w, x01.x, x01.y, x01.z, x01.w};
        float e1[8] = {x10.x, x10.y, x10.z, x10.w, x11.x, x11.y, x11.z, x11.w};
#pragma unroll
        for (int j = 0; j < 8; j++) {
            unsigned short h0 = f2bf(e0[j]);
            unsigned short l0 = f2bf(e0[j] - bf2f(h0));
            unsigned short h1 = f2bf(e1[j]);
            unsigned short l1 = f2bf(e1[j] - bf2f(h1));
            *(unsigned int*)&Bh[c0 + j][2 * rp] = (unsigned int)h0 | ((unsigned int)h1 << 16);
            *(unsigned int*)&Bl[c0 + j][2 * rp] = (unsigned int)l0 | ((unsigned int)l1 << 16);
        }
        __syncthreads();

        bf16x8 bh[4], bl[4];
#pragma unroll
        for (int nt = 0; nt < 4; nt++) {
            bh[nt] = *(const bf16x8*)&Bh[wn * 64 + nt * 16 + lcol][quad * 8];
            bl[nt] = *(const bf16x8*)&Bl[wn * 64 + nt * 16 + lcol][quad * 8];
        }

#pragma unroll
        for (int s = 0; s < 3; s++) {
            const unsigned short* Ws = Wsp + (size_t)s * 65536;
#pragma unroll
            for (int mt = 0; mt < 4; mt++) {
                int m = m0 + wm * 64 + mt * 16 + lcol;
                bf16x8 afr = *(const bf16x8*)&Ws[m * 256 + kk + quad * 8];
#pragma unroll
                for (int nt = 0; nt < 4; nt++)
                    acc[mt][nt] = __builtin_amdgcn_mfma_f32_16x16x32_bf16(
                        afr, bh[nt], acc[mt][nt], 0, 0, 0);
                if (s < 2) {
#pragma unroll
                    for (int nt = 0; nt < 4; nt++)
                        acc[mt][nt] = __builtin_amdgcn_mfma_f32_16x16x32_bf16(
                            afr, bl[nt], acc[mt][nt], 0, 0, 0);
                }
            }
        }
    }

#pragma unroll
    for (int mt = 0; mt < 4; mt++)
#pragma unroll
        for (int i = 0; i < 4; i++) {
            int row = m0 + wm * 64 + mt * 16 + quad * 4 + i;
            float i1 = bnp[1024 + row] / sqrtf(bnp[1024 + 768 + row] + EPSB);
            float b1 = bnp[1024 + 256 + row], m1 = bnp[1024 + 512 + row];
            float i2 = bnp[2048 + row] / sqrtf(bnp[2048 + 768 + row] + EPSB);
            float b2 = bnp[2048 + 256 + row], m2 = bnp[2048 + 512 + row];
            float* yr = &Yt[(size_t)row * N_ + n0 + wn * 64 + lcol];
#pragma unroll
            for (int nt = 0; nt < 4; nt++)
                yr[nt * 16] = ((acc[mt][nt][i] - m1) * i1 + b1 - m2) * i2 + b2;
        }
}

// ---------------------------------------------------------------------------
// Fused BN1 + pad(border=bn1(0)) + 3x3 depthwise (cross-correlation, VALID).
__global__ __launch_bounds__(256) void dw_bn_pad(const float* __restrict__ Yin,
                                                 const float* __restrict__ dw,
                                                 const float* __restrict__ bnp,
                                                 float* __restrict__ Z) {
    int t = blockIdx.z, c = blockIdx.y;
    int x = threadIdx.x & 63;
    int y = blockIdx.x * 4 + (threadIdx.x >> 6);
    const float* Yc = Yin + (size_t)t * CN_ + (size_t)c * N_;

    float w = bnp[c], b = bnp[256 + c], m = bnp[512 + c], var = bnp[768 + c];
    float sq = sqrtf(var + EPSB);
    float inv = w / sq;
    float pad = b - (m * w) / sq;

    float accum = 0.f;
#pragma unroll
    for (int dy = 0; dy < 3; dy++) {
        int yy = y + dy - 1;
#pragma unroll
        for (int dx = 0; dx < 3; dx++) {
            int xx = x + dx - 1;
            float val;
            if (yy < 0 || yy >= 64 || xx < 0 || xx >= 64) val = pad;
            else val = (Yc[yy * 64 + xx] - m) * inv + b;
            accum += dw[c * 9 + dy * 3 + dx] * val;
        }
    }
    Z[(size_t)t * CN_ + (size_t)c * N_ + y * 64 + x] = accum;
}

// ---------------------------------------------------------------------------
// Bitpacked kv: kv[t,h,d,e] = sum_w popcount(K & V).  Exact integer counts.
__global__ __launch_bounds__(1024) void attn_kv_bp(const u64* __restrict__ Kbp,
                                                   const u64* __restrict__ Vbp,
                                                   float* __restrict__ kvbuf) {
    int th = blockIdx.x;
    int t = th >> 3, h = th & 7;
    const u64* kb = Kbp + ((size_t)t * C_ + h * 32) * 64;
    const u64* vb = Vbp + ((size_t)t * C_ + h * 32) * 64;
    __shared__ u64 ks[32][65];
    __shared__ u64 vs[32][65];
    int tid = threadIdx.x;
    {
        int r = tid >> 5, w2 = (tid & 31) * 2;
        ks[r][w2] = kb[r * 64 + w2];     ks[r][w2 + 1] = kb[r * 64 + w2 + 1];
        vs[r][w2] = vb[r * 64 + w2];     vs[r][w2 + 1] = vb[r * 64 + w2 + 1];
    }
    __syncthreads();
    int d = tid >> 5, e = tid & 31;
    int cnt = 0;
#pragma unroll
    for (int w = 0; w < 64; w++)
        cnt += __popcll(ks[d][w] & vs[e][w]);
    kvbuf[(size_t)th * 1024 + d * 32 + e] = (float)cnt;
}

// ---------------------------------------------------------------------------
// o[t, h*32+e, n] = scale * sum_d q[t, h*32+d, n] * kv[t,h,d,e]
__global__ __launch_bounds__(256) void attn_o_u8(const unsigned char* __restrict__ q,
                                                 const float* __restrict__ kvbuf,
                                                 float* __restrict__ o) {
    int t = blockIdx.z, h = blockIdx.y;
    int n = blockIdx.x * 1024 + threadIdx.x * 4;
    __shared__ float kvs[1024];
    const float* kv = kvbuf + (size_t)(t * 8 + h) * 1024;
    for (int i = threadIdx.x; i < 1024; i += 256) kvs[i] = kv[i];
    __syncthreads();
    const unsigned char* qb = q + (size_t)t * CN_ + (size_t)h * 32 * N_ + n;
    float* ob = o + (size_t)t * CN_ + (size_t)h * 32 * N_ + n;
    const float scale = 0.17677669529663687f;
#pragma unroll
    for (int eg = 0; eg < 2; eg++) {
        float acc[16][4];
#pragma unroll
        for (int e = 0; e < 16; e++)
#pragma unroll
            for (int j = 0; j < 4; j++) acc[e][j] = 0.f;
        for (int d = 0; d < 32; d++) {
            uchar4 qu = *(const uchar4*)(&qb[(size_t)d * N_]);
            float4 qv = {(float)qu.x, (float)qu.y, (float)qu.z, (float)qu.w};
#pragma unroll
            for (int e = 0; e < 16; e++) {
                float kvv = kvs[d * 32 + eg * 16 + e];
                acc[e][0] += qv.x * kvv;
                acc[e][1] += qv.y * kvv;
                acc[e][2] += qv.z * kvv;
                acc[e][3] += qv.w * kvv;
            }
        }
#pragma unroll
        for (int e = 0; e < 16; e++) {
            float4 ov = {acc[e][0] * scale, acc[e][1] * scale,
                         acc[e][2] * scale, acc[e][3] * scale};
            *(float4*)(&ob[(size_t)(eg * 16 + e) * N_]) = ov;
        }
    }
}

// ---------------------------------------------------------------------------
extern "C" void kernel_launch(void* const* d_in, const int* in_sizes, int n_in,
                              void* d_out, int out_size, void* d_ws, size_t ws_size,
                              hipStream_t stream) {
    const float* x = (const float*)d_in[0];
    const float* q_w1 = (const float*)d_in[1];
    const float* q_dw = (const float*)d_in[2];
    const float* q_pw = (const float*)d_in[3];
    const float* q_bn = (const float*)d_in[4];
    const float* k_w1 = (const float*)d_in[5];
    const float* k_dw = (const float*)d_in[6];
    const float* k_pw = (const float*)d_in[7];
    const float* k_bn = (const float*)d_in[8];
    const float* v_w1 = (const float*)d_in[9];
    const float* v_dw = (const float*)d_in[10];
    const float* v_pw = (const float*)d_in[11];
    const float* v_bn = (const float*)d_in[12];
    const float* p_w1 = (const float*)d_in[13];
    const float* p_dw = (const float*)d_in[14];
    const float* p_pw = (const float*)d_in[15];
    const float* p_bn = (const float*)d_in[16];

    const size_t SZ = (size_t)T_ * CN_;
    float* out = (float*)d_out;          // fp32 scratch (ping) + final output
    float* S0 = (float*)d_ws;            // fp32 scratch (pong), 33.5 MB
    float* bufKV = S0 + SZ;              // 65,536 floats
    unsigned char* xs = (unsigned char*)(bufKV + 65536);  // u8 spikes (x / o reuse)
    unsigned char* sq = xs + SZ;                          // u8 spikes (q)
    u64* kbp = (u64*)(sq + SZ);
    u64* vbp = kbp + (SZ >> 6);
    unsigned short* wsp = (unsigned short*)(vbp + (SZ >> 6));  // 8*3*65536 bf16
    // total ws: 33.5 + 0.26 + 2*8.39 + 2*1.05 + 3.1 = ~55.8 MB

    dim3 gLif(CN_ / 256), bLif(256);
    dim3 gGemm(N_ / 128, C_ / 128, T_), bGemm(256);
    dim3 gDw(16, C_, T_), bDw(256);

    // exact 3-way bf16 weight splits (order: w1,pw per branch q,k,v,p)
    WPtrs wp;
    wp.w[0] = q_w1; wp.w[1] = q_pw; wp.w[2] = k_w1; wp.w[3] = k_pw;
    wp.w[4] = v_w1; wp.w[5] = v_pw; wp.w[6] = p_w1; wp.w[7] = p_pw;
    split_w<<<dim3(256, 8), dim3(256), 0, stream>>>(wp, wsp);
    const size_t WS3 = 3 * 65536;

    // xs = lif(x)
    lif_u8<<<gLif, bLif, 0, stream>>>(x, xs);

    // q branch
    gemm_s_mfma<<<gGemm, bGemm, 0, stream>>>(wsp + 0 * WS3, xs, out);
    dw_bn_pad<<<gDw, bDw, 0, stream>>>(out, q_dw, q_bn, S0);
    gemm_f_mfma<<<gGemm, bGemm, 0, stream>>>(wsp + 1 * WS3, S0, out, q_bn);
    lif_u8<<<gLif, bLif, 0, stream>>>(out, sq);

    // k branch
    gemm_s_mfma<<<gGemm, bGemm, 0, stream>>>(wsp + 2 * WS3, xs, out);
    dw_bn_pad<<<gDw, bDw, 0, stream>>>(out, k_dw, k_bn, S0);
    gemm_f_mfma<<<gGemm, bGemm, 0, stream>>>(wsp + 3 * WS3, S0, out, k_bn);
    lif_bp<<<gLif, bLif, 0, stream>>>(out, kbp);

    // v branch
    gemm_s_mfma<<<gGemm, bGemm, 0, stream>>>(wsp + 4 * WS3, xs, out);
    dw_bn_pad<<<gDw, bDw, 0, stream>>>(out, v_dw, v_bn, S0);
    gemm_f_mfma<<<gGemm, bGemm, 0, stream>>>(wsp + 5 * WS3, S0, out, v_bn);
    lif_bp<<<gLif, bLif, 0, stream>>>(out, vbp);

    // attention (exact popcount counts), o = q . kv, then lif -> xs
    attn_kv_bp<<<dim3(64), dim3(1024), 0, stream>>>(kbp, vbp, bufKV);
    attn_o_u8<<<dim3(4, 8, 8), dim3(256), 0, stream>>>(sq, bufKV, S0);
    lif_u8<<<gLif, bLif, 0, stream>>>(S0, xs);

    // p branch -> d_out
    gemm_s_mfma<<<gGemm, bGemm, 0, stream>>>(wsp + 6 * WS3, xs, out);
    dw_bn_pad<<<gDw, bDw, 0, stream>>>(out, p_dw, p_bn, S0);
    gemm_f_mfma<<<gGemm, bGemm, 0, stream>>>(wsp + 7 * WS3, S0, out, p_bn);
}

// Round 6
// 697.197 us; speedup vs baseline: 1.4519x; 1.0622x over previous
//
#include <hip/hip_runtime.h>
#include <hip/hip_bf16.h>
#include <math.h>

// Problem constants: B(=T)=8, C=256, H=W=64, N=4096, heads=8, d=32.
#define T_ 8
#define C_ 256
#define N_ 4096          // H*W
#define CN_ (C_ * N_)    // 1048576 elements per timestep
#define EPSB 1e-5f

typedef unsigned long long u64;
typedef short bf16x8 __attribute__((ext_vector_type(8)));
typedef float f32x4 __attribute__((ext_vector_type(4)));

static __device__ __forceinline__ unsigned short f2bf(float f) {
    __hip_bfloat16 h = __float2bfloat16(f);   // RTNE
    return *(unsigned short*)&h;
}
static __device__ __forceinline__ float bf2f(unsigned short u) {
    unsigned int x = (unsigned int)u << 16;   // exact widen
    return *(float*)&x;
}

// ---------------------------------------------------------------------------
// LIF scan over t: u8 spikes.
__global__ __launch_bounds__(256) void lif_u8(const float* __restrict__ X,
                                              unsigned char* __restrict__ S) {
    int idx = blockIdx.x * 256 + threadIdx.x;
    float v = 0.f;
#pragma unroll
    for (int t = 0; t < T_; t++) {
        float xt = X[(size_t)t * CN_ + idx];
        v = v + (xt - v) / 2.0f;
        unsigned char s = (v - 1.0f >= 0.f) ? 1 : 0;
        S[(size_t)t * CN_ + idx] = s;
        if (s) v = 0.f;
    }
}

// LIF writing bitpacked spikes (bit l of word w = n = w*64+l).
__global__ __launch_bounds__(256) void lif_bp(const float* __restrict__ X,
                                              u64* __restrict__ BP) {
    int idx = blockIdx.x * 256 + threadIdx.x;
    int lane = threadIdx.x & 63;
    float v = 0.f;
#pragma unroll
    for (int t = 0; t < T_; t++) {
        float xt = X[(size_t)t * CN_ + idx];
        v = v + (xt - v) / 2.0f;
        int s = (v - 1.0f >= 0.f) ? 1 : 0;
        u64 mask = __ballot(s);
        if (lane == 0) BP[((size_t)t * CN_ + idx) >> 6] = mask;
        if (s) v = 0.f;
    }
}

// ---------------------------------------------------------------------------
// Exact 3-way bf16 split of the eight 256x256 weight matrices.
// out layout: [mat 8][split 3][256*256] bf16 bits.
struct WPtrs { const float* w[8]; };
__global__ __launch_bounds__(256) void split_w(WPtrs p, unsigned short* __restrict__ out) {
    int mat = blockIdx.y;
    int idx = blockIdx.x * 256 + threadIdx.x;   // < 65536
    float w = p.w[mat][idx];
    unsigned short h1 = f2bf(w);
    float f1 = bf2f(h1);
    unsigned short h2 = f2bf(w - f1);
    float f2v = bf2f(h2);
    unsigned short h3 = f2bf(w - f1 - f2v);     // exact: 8+8+8 bits cover fp32
    size_t base = (size_t)mat * 3 * 65536 + idx;
    out[base] = h1;
    out[base + 65536] = h2;
    out[base + 2 * 65536] = h3;
}

// ---------------------------------------------------------------------------
// MFMA GEMM, B = u8 spikes (exact in bf16): Y[t][m][n] = sum_k W[m][k]*S[t][k][n].
// 128x128 tile, 4 waves 2x2, BK=32. Staging: thread owns one n-column,
// gathers 16 k-values coalesced from global, writes its own LDS row (pad 36).
__global__ __launch_bounds__(256) void gemm_s_mfma(const unsigned short* __restrict__ Wsp,
                                                   const unsigned char* __restrict__ S,
                                                   float* __restrict__ Y) {
    int t = blockIdx.z;
    const unsigned char* St = S + (size_t)t * CN_;
    float* Yt = Y + (size_t)t * CN_;
    int m0 = blockIdx.y * 128, n0 = blockIdx.x * 128;
    int tid = threadIdx.x;
    int lane = tid & 63, wave = tid >> 6;
    int wm = wave >> 1, wn = wave & 1;
    int lcol = lane & 15, quad = lane >> 4;

    __shared__ unsigned short Bs[128][36];   // [n][k], row pad 72B -> 2-way free

    f32x4 acc[4][4];
#pragma unroll
    for (int i = 0; i < 4; i++)
#pragma unroll
        for (int j = 0; j < 4; j++) acc[i][j] = (f32x4){0.f, 0.f, 0.f, 0.f};

    int sn = tid & 127;          // n within tile
    int skg = (tid >> 7) * 16;   // k start within BK: 0 or 16

    for (int kk = 0; kk < 256; kk += 32) {
        unsigned char sv[16];
#pragma unroll
        for (int j = 0; j < 16; j++)
            sv[j] = St[(size_t)(kk + skg + j) * N_ + n0 + sn];
        __syncthreads();
        bf16x8 v0, v1;
#pragma unroll
        for (int j = 0; j < 8; j++) {
            v0[j] = sv[j] ? (short)0x3F80 : (short)0;
            v1[j] = sv[8 + j] ? (short)0x3F80 : (short)0;
        }
        *(bf16x8*)&Bs[sn][skg] = v0;
        *(bf16x8*)&Bs[sn][skg + 8] = v1;
        __syncthreads();

        bf16x8 bfr[4];
#pragma unroll
        for (int nt = 0; nt < 4; nt++)
            bfr[nt] = *(const bf16x8*)&Bs[wn * 64 + nt * 16 + lcol][quad * 8];

#pragma unroll
        for (int s = 0; s < 3; s++) {
            const unsigned short* Ws = Wsp + (size_t)s * 65536;
#pragma unroll
            for (int mt = 0; mt < 4; mt++) {
                int m = m0 + wm * 64 + mt * 16 + lcol;
                bf16x8 afr = *(const bf16x8*)&Ws[m * 256 + kk + quad * 8];
#pragma unroll
                for (int nt = 0; nt < 4; nt++)
                    acc[mt][nt] = __builtin_amdgcn_mfma_f32_16x16x32_bf16(
                        afr, bfr[nt], acc[mt][nt], 0, 0, 0);
            }
        }
    }

#pragma unroll
    for (int mt = 0; mt < 4; mt++)
#pragma unroll
        for (int i = 0; i < 4; i++) {
            int row = m0 + wm * 64 + mt * 16 + quad * 4 + i;
            float* yr = &Yt[(size_t)row * N_ + n0 + wn * 64 + lcol];
#pragma unroll
            for (int nt = 0; nt < 4; nt++) yr[nt * 16] = acc[mt][nt][i];
        }
}

// ---------------------------------------------------------------------------
// MFMA GEMM, B = fp32 (2-way bf16 split), fused BN(j=1)->BN(j=2) epilogue.
// Passes: a1b1, a1b2, a2b1, a2b2, a3b1 (terms >= 2^-18 significance).
__global__ __launch_bounds__(256) void gemm_f_mfma(const unsigned short* __restrict__ Wsp,
                                                   const float* __restrict__ X,
                                                   float* __restrict__ Y,
                                                   const float* __restrict__ bnp) {
    int t = blockIdx.z;
    const float* Xt = X + (size_t)t * CN_;
    float* Yt = Y + (size_t)t * CN_;
    int m0 = blockIdx.y * 128, n0 = blockIdx.x * 128;
    int tid = threadIdx.x;
    int lane = tid & 63, wave = tid >> 6;
    int wm = wave >> 1, wn = wave & 1;
    int lcol = lane & 15, quad = lane >> 4;

    __shared__ unsigned short Bh[128][36];
    __shared__ unsigned short Bl[128][36];

    f32x4 acc[4][4];
#pragma unroll
    for (int i = 0; i < 4; i++)
#pragma unroll
        for (int j = 0; j < 4; j++) acc[i][j] = (f32x4){0.f, 0.f, 0.f, 0.f};

    int sn = tid & 127;
    int skg = (tid >> 7) * 16;

    for (int kk = 0; kk < 256; kk += 32) {
        float xv[16];
#pragma unroll
        for (int j = 0; j < 16; j++)
            xv[j] = Xt[(size_t)(kk + skg + j) * N_ + n0 + sn];
        __syncthreads();
        bf16x8 vh0, vh1, vl0, vl1;
#pragma unroll
        for (int j = 0; j < 8; j++) {
            unsigned short h0 = f2bf(xv[j]);
            vh0[j] = (short)h0;
            vl0[j] = (short)f2bf(xv[j] - bf2f(h0));
            unsigned short h1 = f2bf(xv[8 + j]);
            vh1[j] = (short)h1;
            vl1[j] = (short)f2bf(xv[8 + j] - bf2f(h1));
        }
        *(bf16x8*)&Bh[sn][skg] = vh0;
        *(bf16x8*)&Bh[sn][skg + 8] = vh1;
        *(bf16x8*)&Bl[sn][skg] = vl0;
        *(bf16x8*)&Bl[sn][skg + 8] = vl1;
        __syncthreads();

        bf16x8 bh[4], bl[4];
#pragma unroll
        for (int nt = 0; nt < 4; nt++) {
            bh[nt] = *(const bf16x8*)&Bh[wn * 64 + nt * 16 + lcol][quad * 8];
            bl[nt] = *(const bf16x8*)&Bl[wn * 64 + nt * 16 + lcol][quad * 8];
        }

#pragma unroll
        for (int s = 0; s < 3; s++) {
            const unsigned short* Ws = Wsp + (size_t)s * 65536;
#pragma unroll
            for (int mt = 0; mt < 4; mt++) {
                int m = m0 + wm * 64 + mt * 16 + lcol;
                bf16x8 afr = *(const bf16x8*)&Ws[m * 256 + kk + quad * 8];
#pragma unroll
                for (int nt = 0; nt < 4; nt++)
                    acc[mt][nt] = __builtin_amdgcn_mfma_f32_16x16x32_bf16(
                        afr, bh[nt], acc[mt][nt], 0, 0, 0);
                if (s < 2) {
#pragma unroll
                    for (int nt = 0; nt < 4; nt++)
                        acc[mt][nt] = __builtin_amdgcn_mfma_f32_16x16x32_bf16(
                            afr, bl[nt], acc[mt][nt], 0, 0, 0);
                }
            }
        }
    }

#pragma unroll
    for (int mt = 0; mt < 4; mt++)
#pragma unroll
        for (int i = 0; i < 4; i++) {
            int row = m0 + wm * 64 + mt * 16 + quad * 4 + i;
            float i1 = bnp[1024 + row] / sqrtf(bnp[1024 + 768 + row] + EPSB);
            float b1 = bnp[1024 + 256 + row], m1 = bnp[1024 + 512 + row];
            float i2 = bnp[2048 + row] / sqrtf(bnp[2048 + 768 + row] + EPSB);
            float b2 = bnp[2048 + 256 + row], m2 = bnp[2048 + 512 + row];
            float* yr = &Yt[(size_t)row * N_ + n0 + wn * 64 + lcol];
#pragma unroll
            for (int nt = 0; nt < 4; nt++)
                yr[nt * 16] = ((acc[mt][nt][i] - m1) * i1 + b1 - m2) * i2 + b2;
        }
}

// ---------------------------------------------------------------------------
// Fused BN1 + pad(border=bn1(0)) + 3x3 depthwise (cross-correlation, VALID).
__global__ __launch_bounds__(256) void dw_bn_pad(const float* __restrict__ Yin,
                                                 const float* __restrict__ dw,
                                                 const float* __restrict__ bnp,
                                                 float* __restrict__ Z) {
    int t = blockIdx.z, c = blockIdx.y;
    int x = threadIdx.x & 63;
    int y = blockIdx.x * 4 + (threadIdx.x >> 6);
    const float* Yc = Yin + (size_t)t * CN_ + (size_t)c * N_;

    float w = bnp[c], b = bnp[256 + c], m = bnp[512 + c], var = bnp[768 + c];
    float sq = sqrtf(var + EPSB);
    float inv = w / sq;
    float pad = b - (m * w) / sq;

    float accum = 0.f;
#pragma unroll
    for (int dy = 0; dy < 3; dy++) {
        int yy = y + dy - 1;
#pragma unroll
        for (int dx = 0; dx < 3; dx++) {
            int xx = x + dx - 1;
            float val;
            if (yy < 0 || yy >= 64 || xx < 0 || xx >= 64) val = pad;
            else val = (Yc[yy * 64 + xx] - m) * inv + b;
            accum += dw[c * 9 + dy * 3 + dx] * val;
        }
    }
    Z[(size_t)t * CN_ + (size_t)c * N_ + y * 64 + x] = accum;
}

// ---------------------------------------------------------------------------
// Bitpacked kv: kv[t,h,d,e] = sum_w popcount(K & V).  Exact integer counts.
__global__ __launch_bounds__(1024) void attn_kv_bp(const u64* __restrict__ Kbp,
                                                   const u64* __restrict__ Vbp,
                                                   float* __restrict__ kvbuf) {
    int th = blockIdx.x;
    int t = th >> 3, h = th & 7;
    const u64* kb = Kbp + ((size_t)t * C_ + h * 32) * 64;
    const u64* vb = Vbp + ((size_t)t * C_ + h * 32) * 64;
    __shared__ u64 ks[32][65];
    __shared__ u64 vs[32][65];
    int tid = threadIdx.x;
    {
        int r = tid >> 5, w2 = (tid & 31) * 2;
        ks[r][w2] = kb[r * 64 + w2];     ks[r][w2 + 1] = kb[r * 64 + w2 + 1];
        vs[r][w2] = vb[r * 64 + w2];     vs[r][w2 + 1] = vb[r * 64 + w2 + 1];
    }
    __syncthreads();
    int d = tid >> 5, e = tid & 31;
    int cnt = 0;
#pragma unroll
    for (int w = 0; w < 64; w++)
        cnt += __popcll(ks[d][w] & vs[e][w]);
    kvbuf[(size_t)th * 1024 + d * 32 + e] = (float)cnt;
}

// ---------------------------------------------------------------------------
// o[t, h*32+e, n] = scale * sum_d q[t, h*32+d, n] * kv[t,h,d,e]
__global__ __launch_bounds__(256) void attn_o_u8(const unsigned char* __restrict__ q,
                                                 const float* __restrict__ kvbuf,
                                                 float* __restrict__ o) {
    int t = blockIdx.z, h = blockIdx.y;
    int n = blockIdx.x * 1024 + threadIdx.x * 4;
    __shared__ float kvs[1024];
    const float* kv = kvbuf + (size_t)(t * 8 + h) * 1024;
    for (int i = threadIdx.x; i < 1024; i += 256) kvs[i] = kv[i];
    __syncthreads();
    const unsigned char* qb = q + (size_t)t * CN_ + (size_t)h * 32 * N_ + n;
    float* ob = o + (size_t)t * CN_ + (size_t)h * 32 * N_ + n;
    const float scale = 0.17677669529663687f;
#pragma unroll
    for (int eg = 0; eg < 2; eg++) {
        float acc[16][4];
#pragma unroll
        for (int e = 0; e < 16; e++)
#pragma unroll
            for (int j = 0; j < 4; j++) acc[e][j] = 0.f;
        for (int d = 0; d < 32; d++) {
            uchar4 qu = *(const uchar4*)(&qb[(size_t)d * N_]);
            float4 qv = {(float)qu.x, (float)qu.y, (float)qu.z, (float)qu.w};
#pragma unroll
            for (int e = 0; e < 16; e++) {
                float kvv = kvs[d * 32 + eg * 16 + e];
                acc[e][0] += qv.x * kvv;
                acc[e][1] += qv.y * kvv;
                acc[e][2] += qv.z * kvv;
                acc[e][3] += qv.w * kvv;
            }
        }
#pragma unroll
        for (int e = 0; e < 16; e++) {
            float4 ov = {acc[e][0] * scale, acc[e][1] * scale,
                         acc[e][2] * scale, acc[e][3] * scale};
            *(float4*)(&ob[(size_t)(eg * 16 + e) * N_]) = ov;
        }
    }
}

// ---------------------------------------------------------------------------
extern "C" void kernel_launch(void* const* d_in, const int* in_sizes, int n_in,
                              void* d_out, int out_size, void* d_ws, size_t ws_size,
                              hipStream_t stream) {
    const float* x = (const float*)d_in[0];
    const float* q_w1 = (const float*)d_in[1];
    const float* q_dw = (const float*)d_in[2];
    const float* q_pw = (const float*)d_in[3];
    const float* q_bn = (const float*)d_in[4];
    const float* k_w1 = (const float*)d_in[5];
    const float* k_dw = (const float*)d_in[6];
    const float* k_pw = (const float*)d_in[7];
    const float* k_bn = (const float*)d_in[8];
    const float* v_w1 = (const float*)d_in[9];
    const float* v_dw = (const float*)d_in[10];
    const float* v_pw = (const float*)d_in[11];
    const float* v_bn = (const float*)d_in[12];
    const float* p_w1 = (const float*)d_in[13];
    const float* p_dw = (const float*)d_in[14];
    const float* p_pw = (const float*)d_in[15];
    const float* p_bn = (const float*)d_in[16];

    const size_t SZ = (size_t)T_ * CN_;
    float* out = (float*)d_out;          // fp32 scratch (ping) + final output
    float* S0 = (float*)d_ws;            // fp32 scratch (pong), 33.5 MB
    float* bufKV = S0 + SZ;              // 65,536 floats
    unsigned char* xs = (unsigned char*)(bufKV + 65536);  // u8 spikes (x / o reuse)
    unsigned char* sq = xs + SZ;                          // u8 spikes (q)
    u64* kbp = (u64*)(sq + SZ);
    u64* vbp = kbp + (SZ >> 6);
    unsigned short* wsp = (unsigned short*)(vbp + (SZ >> 6));  // 8*3*65536 bf16
    // total ws: 33.5 + 0.26 + 2*8.39 + 2*1.05 + 3.1 = ~55.8 MB

    dim3 gLif(CN_ / 256), bLif(256);
    dim3 gGemm(N_ / 128, C_ / 128, T_), bGemm(256);
    dim3 gDw(16, C_, T_), bDw(256);

    // exact 3-way bf16 weight splits (order: w1,pw per branch q,k,v,p)
    WPtrs wp;
    wp.w[0] = q_w1; wp.w[1] = q_pw; wp.w[2] = k_w1; wp.w[3] = k_pw;
    wp.w[4] = v_w1; wp.w[5] = v_pw; wp.w[6] = p_w1; wp.w[7] = p_pw;
    split_w<<<dim3(256, 8), dim3(256), 0, stream>>>(wp, wsp);
    const size_t WS3 = 3 * 65536;

    // xs = lif(x)
    lif_u8<<<gLif, bLif, 0, stream>>>(x, xs);

    // q branch
    gemm_s_mfma<<<gGemm, bGemm, 0, stream>>>(wsp + 0 * WS3, xs, out);
    dw_bn_pad<<<gDw, bDw, 0, stream>>>(out, q_dw, q_bn, S0);
    gemm_f_mfma<<<gGemm, bGemm, 0, stream>>>(wsp + 1 * WS3, S0, out, q_bn);
    lif_u8<<<gLif, bLif, 0, stream>>>(out, sq);

    // k branch
    gemm_s_mfma<<<gGemm, bGemm, 0, stream>>>(wsp + 2 * WS3, xs, out);
    dw_bn_pad<<<gDw, bDw, 0, stream>>>(out, k_dw, k_bn, S0);
    gemm_f_mfma<<<gGemm, bGemm, 0, stream>>>(wsp + 3 * WS3, S0, out, k_bn);
    lif_bp<<<gLif, bLif, 0, stream>>>(out, kbp);

    // v branch
    gemm_s_mfma<<<gGemm, bGemm, 0, stream>>>(wsp + 4 * WS3, xs, out);
    dw_bn_pad<<<gDw, bDw, 0, stream>>>(out, v_dw, v_bn, S0);
    gemm_f_mfma<<<gGemm, bGemm, 0, stream>>>(wsp + 5 * WS3, S0, out, v_bn);
    lif_bp<<<gLif, bLif, 0, stream>>>(out, vbp);

    // attention (exact popcount counts), o = q . kv, then lif -> xs
    attn_kv_bp<<<dim3(64), dim3(1024), 0, stream>>>(kbp, vbp, bufKV);
    attn_o_u8<<<dim3(4, 8, 8), dim3(256), 0, stream>>>(sq, bufKV, S0);
    lif_u8<<<gLif, bLif, 0, stream>>>(S0, xs);

    // p branch -> d_out
    gemm_s_mfma<<<gGemm, bGemm, 0, stream>>>(wsp + 6 * WS3, xs, out);
    dw_bn_pad<<<gDw, bDw, 0, stream>>>(out, p_dw, p_bn, S0);
    gemm_f_mfma<<<gGemm, bGemm, 0, stream>>>(wsp + 7 * WS3, S0, out, p_bn);
}

// Round 7
// 631.203 us; speedup vs baseline: 1.6037x; 1.1046x over previous
//
#include <hip/hip_runtime.h>
#include <hip/hip_bf16.h>
#include <math.h>

// Problem constants: B(=T)=8, C=256, H=W=64, N=4096, heads=8, d=32.
#define T_ 8
#define C_ 256
#define N_ 4096          // H*W
#define CN_ (C_ * N_)    // 1048576 elements per timestep
#define EPSB 1e-5f

typedef unsigned long long u64;
typedef unsigned int u32;
typedef short bf16x8 __attribute__((ext_vector_type(8)));
typedef float f32x4 __attribute__((ext_vector_type(4)));

static __device__ __forceinline__ unsigned short f2bf(float f) {
    __hip_bfloat16 h = __float2bfloat16(f);   // RTNE
    return *(unsigned short*)&h;
}
static __device__ __forceinline__ float bf2f(unsigned short u) {
    u32 x = (u32)u << 16;                     // exact widen
    return *(float*)&x;
}

// Fragment tiling (both operands of mfma_f32_16x16x32_bf16 are k-contiguous):
// a 16(row) x 32(k) tile is stored as [lane 64][8 shorts], lane = ((k>>3)&3)*16
// + (row&15), j = k&7.  Tile stride = 512 shorts.  Tiles indexed [r16][k32].

// ---------------------------------------------------------------------------
// LIF scan over t: u8 spikes.
__global__ __launch_bounds__(256) void lif_u8(const float* __restrict__ X,
                                              unsigned char* __restrict__ S) {
    int idx = blockIdx.x * 256 + threadIdx.x;
    float v = 0.f;
#pragma unroll
    for (int t = 0; t < T_; t++) {
        float xt = X[(size_t)t * CN_ + idx];
        v = v + (xt - v) / 2.0f;
        unsigned char s = (v - 1.0f >= 0.f) ? 1 : 0;
        S[(size_t)t * CN_ + idx] = s;
        if (s) v = 0.f;
    }
}

// LIF writing bitpacked spikes (bit l of word w = n = w*64+l).
__global__ __launch_bounds__(256) void lif_bp(const float* __restrict__ X,
                                              u64* __restrict__ BP) {
    int idx = blockIdx.x * 256 + threadIdx.x;
    int lane = threadIdx.x & 63;
    float v = 0.f;
#pragma unroll
    for (int t = 0; t < T_; t++) {
        float xt = X[(size_t)t * CN_ + idx];
        v = v + (xt - v) / 2.0f;
        int s = (v - 1.0f >= 0.f) ? 1 : 0;
        u64 mask = __ballot(s);
        if (lane == 0) BP[((size_t)t * CN_ + idx) >> 6] = mask;
        if (s) v = 0.f;
    }
}

// ---------------------------------------------------------------------------
// Exact 3-way bf16 split of the eight 256x256 weights -> A-fragment layout.
// out: [mat 8][split 3][m16 16][k32 8][lane 64][8].
struct WPtrs { const float* w[8]; };
__global__ __launch_bounds__(256) void split_w(WPtrs p, unsigned short* __restrict__ out) {
    int mat = blockIdx.y;
    int idx = blockIdx.x * 256 + threadIdx.x;   // = m*256 + k
    int m = idx >> 8, k = idx & 255;
    float w = p.w[mat][idx];
    unsigned short h1 = f2bf(w);
    float f1 = bf2f(h1);
    unsigned short h2 = f2bf(w - f1);
    unsigned short h3 = f2bf(w - f1 - bf2f(h2));   // exact: 8+8+8 bits
    int lane = ((k >> 3) & 3) * 16 + (m & 15);
    size_t pos = ((size_t)(((m >> 4) * 8 + (k >> 5)) * 64 + lane)) * 8 + (k & 7);
    size_t base = (size_t)mat * 3 * 65536;
    out[base + pos] = h1;
    out[base + 65536 + pos] = h2;
    out[base + 2 * 65536 + pos] = h3;
}

// ---------------------------------------------------------------------------
// u8 spikes [t][k][n] -> bf16 B-fragment layout (per t: [n16 256][k32 8][512]).
__global__ __launch_bounds__(256) void trans_s(const unsigned char* __restrict__ S,
                                               unsigned short* __restrict__ ST) {
    int t = blockIdx.y;
    int nb = blockIdx.x * 32;
    const unsigned char* St = S + (size_t)t * CN_;
    __shared__ u32 L[32][257];
    int tid = threadIdx.x;
    int nof = (tid & 7) * 4;
    int kbase = tid >> 3;
#pragma unroll
    for (int it = 0; it < 8; it++) {
        int k = kbase + it * 32;
        uchar4 sv = *(const uchar4*)&St[(size_t)k * N_ + nb + nof];
        L[nof + 0][k] = sv.x ? 0x3F80u : 0u;
        L[nof + 1][k] = sv.y ? 0x3F80u : 0u;
        L[nof + 2][k] = sv.z ? 0x3F80u : 0u;
        L[nof + 3][k] = sv.w ? 0x3F80u : 0u;
    }
    __syncthreads();
    int n = tid & 31, k32 = tid >> 5;
    int n16 = (nb + n) >> 4;
    int lrow = n & 15;
    unsigned short* outt = ST + (size_t)t * CN_;
#pragma unroll
    for (int quad = 0; quad < 4; quad++) {
        bf16x8 bs;
#pragma unroll
        for (int j = 0; j < 8; j++)
            bs[j] = (short)(L[n][k32 * 32 + quad * 8 + j] & 0xffffu);
        *(bf16x8*)&outt[((size_t)(n16 * 8 + k32)) * 512 + (quad * 16 + lrow) * 8] = bs;
    }
}

// ---------------------------------------------------------------------------
// fp32 [t][k][n] -> exact (hi,lo) bf16 pair, both in B-fragment layout.
__global__ __launch_bounds__(256) void trans_split(const float* __restrict__ X,
                                                   unsigned short* __restrict__ BhT,
                                                   unsigned short* __restrict__ BlT) {
    int t = blockIdx.y;
    int nb = blockIdx.x * 32;
    const float* Xt = X + (size_t)t * CN_;
    __shared__ u32 L[32][257];
    int tid = threadIdx.x;
    int nof = (tid & 7) * 4;
    int kbase = tid >> 3;
#pragma unroll
    for (int it = 0; it < 8; it++) {
        int k = kbase + it * 32;
        float4 xv = *(const float4*)&Xt[(size_t)k * N_ + nb + nof];
        float e[4] = {xv.x, xv.y, xv.z, xv.w};
#pragma unroll
        for (int j = 0; j < 4; j++) {
            unsigned short h = f2bf(e[j]);
            unsigned short lo = f2bf(e[j] - bf2f(h));
            L[nof + j][k] = (u32)h | ((u32)lo << 16);
        }
    }
    __syncthreads();
    int n = tid & 31, k32 = tid >> 5;
    int n16 = (nb + n) >> 4;
    int lrow = n & 15;
    unsigned short* oh = BhT + (size_t)t * CN_;
    unsigned short* ol = BlT + (size_t)t * CN_;
#pragma unroll
    for (int quad = 0; quad < 4; quad++) {
        bf16x8 bh, bl;
#pragma unroll
        for (int j = 0; j < 8; j++) {
            u32 w = L[n][k32 * 32 + quad * 8 + j];
            bh[j] = (short)(w & 0xffffu);
            bl[j] = (short)(w >> 16);
        }
        size_t pos = ((size_t)(n16 * 8 + k32)) * 512 + (quad * 16 + lrow) * 8;
        *(bf16x8*)&oh[pos] = bh;
        *(bf16x8*)&ol[pos] = bl;
    }
}

// ---------------------------------------------------------------------------
// LDS-free MFMA GEMM, B = spike bf16 fragments (exact): 3 A-splits.
__global__ __launch_bounds__(256) void gemm_s2(const unsigned short* __restrict__ Wsp,
                                               const unsigned short* __restrict__ ST,
                                               float* __restrict__ Y) {
    int t = blockIdx.z;
    const unsigned short* Bt = ST + (size_t)t * CN_;
    float* Yt = Y + (size_t)t * CN_;
    int bx = blockIdx.x, by = blockIdx.y;
    int tid = threadIdx.x, l = tid & 63, wave = tid >> 6;
    int wm = wave >> 1, wn = wave & 1;
    int lcol = l & 15, quad = l >> 4;

    f32x4 acc[4][4];
#pragma unroll
    for (int i = 0; i < 4; i++)
#pragma unroll
        for (int j = 0; j < 4; j++) acc[i][j] = (f32x4){0.f, 0.f, 0.f, 0.f};

#pragma unroll 2
    for (int k32 = 0; k32 < 8; k32++) {
        bf16x8 bfr[4];
#pragma unroll
        for (int nt = 0; nt < 4; nt++)
            bfr[nt] = *(const bf16x8*)&Bt[((size_t)((bx * 8 + wn * 4 + nt) * 8 + k32)) * 512 + l * 8];
#pragma unroll
        for (int s = 0; s < 3; s++) {
            const unsigned short* Ws = Wsp + (size_t)s * 65536;
#pragma unroll
            for (int mt = 0; mt < 4; mt++) {
                bf16x8 afr = *(const bf16x8*)&Ws[((size_t)((by * 8 + wm * 4 + mt) * 8 + k32)) * 512 + l * 8];
#pragma unroll
                for (int nt = 0; nt < 4; nt++)
                    acc[mt][nt] = __builtin_amdgcn_mfma_f32_16x16x32_bf16(
                        afr, bfr[nt], acc[mt][nt], 0, 0, 0);
            }
        }
    }

    int m0 = by * 128, n0 = bx * 128;
#pragma unroll
    for (int mt = 0; mt < 4; mt++)
#pragma unroll
        for (int i = 0; i < 4; i++) {
            int row = m0 + wm * 64 + mt * 16 + quad * 4 + i;
            float* yr = &Yt[(size_t)row * N_ + n0 + wn * 64 + lcol];
#pragma unroll
            for (int nt = 0; nt < 4; nt++) yr[nt * 16] = acc[mt][nt][i];
        }
}

// ---------------------------------------------------------------------------
// LDS-free MFMA GEMM, B = (hi,lo) bf16 fragments; passes a1(b1+b2),a2(b1+b2),
// a3b1; fused BN(j=1)->BN(j=2) epilogue.
__global__ __launch_bounds__(256) void gemm_f2(const unsigned short* __restrict__ Wsp,
                                               const unsigned short* __restrict__ BhT,
                                               const unsigned short* __restrict__ BlT,
                                               float* __restrict__ Y,
                                               const float* __restrict__ bnp) {
    int t = blockIdx.z;
    const unsigned short* Bht = BhT + (size_t)t * CN_;
    const unsigned short* Blt = BlT + (size_t)t * CN_;
    float* Yt = Y + (size_t)t * CN_;
    int bx = blockIdx.x, by = blockIdx.y;
    int tid = threadIdx.x, l = tid & 63, wave = tid >> 6;
    int wm = wave >> 1, wn = wave & 1;
    int lcol = l & 15, quad = l >> 4;

    f32x4 acc[4][4];
#pragma unroll
    for (int i = 0; i < 4; i++)
#pragma unroll
        for (int j = 0; j < 4; j++) acc[i][j] = (f32x4){0.f, 0.f, 0.f, 0.f};

#pragma unroll 2
    for (int k32 = 0; k32 < 8; k32++) {
        bf16x8 bh[4], bl[4];
#pragma unroll
        for (int nt = 0; nt < 4; nt++) {
            size_t bpos = ((size_t)((bx * 8 + wn * 4 + nt) * 8 + k32)) * 512 + l * 8;
            bh[nt] = *(const bf16x8*)&Bht[bpos];
            bl[nt] = *(const bf16x8*)&Blt[bpos];
        }
#pragma unroll
        for (int s = 0; s < 3; s++) {
            const unsigned short* Ws = Wsp + (size_t)s * 65536;
#pragma unroll
            for (int mt = 0; mt < 4; mt++) {
                bf16x8 afr = *(const bf16x8*)&Ws[((size_t)((by * 8 + wm * 4 + mt) * 8 + k32)) * 512 + l * 8];
#pragma unroll
                for (int nt = 0; nt < 4; nt++)
                    acc[mt][nt] = __builtin_amdgcn_mfma_f32_16x16x32_bf16(
                        afr, bh[nt], acc[mt][nt], 0, 0, 0);
                if (s < 2) {
#pragma unroll
                    for (int nt = 0; nt < 4; nt++)
                        acc[mt][nt] = __builtin_amdgcn_mfma_f32_16x16x32_bf16(
                            afr, bl[nt], acc[mt][nt], 0, 0, 0);
                }
            }
        }
    }

    int m0 = by * 128, n0 = bx * 128;
#pragma unroll
    for (int mt = 0; mt < 4; mt++)
#pragma unroll
        for (int i = 0; i < 4; i++) {
            int row = m0 + wm * 64 + mt * 16 + quad * 4 + i;
            float i1 = bnp[1024 + row] / sqrtf(bnp[1024 + 768 + row] + EPSB);
            float b1 = bnp[1024 + 256 + row], m1 = bnp[1024 + 512 + row];
            float i2 = bnp[2048 + row] / sqrtf(bnp[2048 + 768 + row] + EPSB);
            float b2 = bnp[2048 + 256 + row], m2 = bnp[2048 + 512 + row];
            float* yr = &Yt[(size_t)row * N_ + n0 + wn * 64 + lcol];
#pragma unroll
            for (int nt = 0; nt < 4; nt++)
                yr[nt * 16] = ((acc[mt][nt][i] - m1) * i1 + b1 - m2) * i2 + b2;
        }
}

// ---------------------------------------------------------------------------
// Fused BN1 + pad(border=bn1(0)) + 3x3 depthwise (cross-correlation, VALID).
__global__ __launch_bounds__(256) void dw_bn_pad(const float* __restrict__ Yin,
                                                 const float* __restrict__ dw,
                                                 const float* __restrict__ bnp,
                                                 float* __restrict__ Z) {
    int t = blockIdx.z, c = blockIdx.y;
    int x = threadIdx.x & 63;
    int y = blockIdx.x * 4 + (threadIdx.x >> 6);
    const float* Yc = Yin + (size_t)t * CN_ + (size_t)c * N_;

    float w = bnp[c], b = bnp[256 + c], m = bnp[512 + c], var = bnp[768 + c];
    float sq = sqrtf(var + EPSB);
    float inv = w / sq;
    float pad = b - (m * w) / sq;

    float accum = 0.f;
#pragma unroll
    for (int dy = 0; dy < 3; dy++) {
        int yy = y + dy - 1;
#pragma unroll
        for (int dx = 0; dx < 3; dx++) {
            int xx = x + dx - 1;
            float val;
            if (yy < 0 || yy >= 64 || xx < 0 || xx >= 64) val = pad;
            else val = (Yc[yy * 64 + xx] - m) * inv + b;
            accum += dw[c * 9 + dy * 3 + dx] * val;
        }
    }
    Z[(size_t)t * CN_ + (size_t)c * N_ + y * 64 + x] = accum;
}

// ---------------------------------------------------------------------------
// Bitpacked kv: kv[t,h,d,e] = sum_w popcount(K & V).  Exact integer counts.
__global__ __launch_bounds__(1024) void attn_kv_bp(const u64* __restrict__ Kbp,
                                                   const u64* __restrict__ Vbp,
                                                   float* __restrict__ kvbuf) {
    int th = blockIdx.x;
    int t = th >> 3, h = th & 7;
    const u64* kb = Kbp + ((size_t)t * C_ + h * 32) * 64;
    const u64* vb = Vbp + ((size_t)t * C_ + h * 32) * 64;
    __shared__ u64 ks[32][65];
    __shared__ u64 vs[32][65];
    int tid = threadIdx.x;
    {
        int r = tid >> 5, w2 = (tid & 31) * 2;
        ks[r][w2] = kb[r * 64 + w2];     ks[r][w2 + 1] = kb[r * 64 + w2 + 1];
        vs[r][w2] = vb[r * 64 + w2];     vs[r][w2 + 1] = vb[r * 64 + w2 + 1];
    }
    __syncthreads();
    int d = tid >> 5, e = tid & 31;
    int cnt = 0;
#pragma unroll
    for (int w = 0; w < 64; w++)
        cnt += __popcll(ks[d][w] & vs[e][w]);
    kvbuf[(size_t)th * 1024 + d * 32 + e] = (float)cnt;
}

// ---------------------------------------------------------------------------
// o[t, h*32+e, n] = scale * sum_d q[t, h*32+d, n] * kv[t,h,d,e]
__global__ __launch_bounds__(256) void attn_o_u8(const unsigned char* __restrict__ q,
                                                 const float* __restrict__ kvbuf,
                                                 float* __restrict__ o) {
    int t = blockIdx.z, h = blockIdx.y;
    int n = blockIdx.x * 1024 + threadIdx.x * 4;
    __shared__ float kvs[1024];
    const float* kv = kvbuf + (size_t)(t * 8 + h) * 1024;
    for (int i = threadIdx.x; i < 1024; i += 256) kvs[i] = kv[i];
    __syncthreads();
    const unsigned char* qb = q + (size_t)t * CN_ + (size_t)h * 32 * N_ + n;
    float* ob = o + (size_t)t * CN_ + (size_t)h * 32 * N_ + n;
    const float scale = 0.17677669529663687f;
#pragma unroll
    for (int eg = 0; eg < 2; eg++) {
        float acc[16][4];
#pragma unroll
        for (int e = 0; e < 16; e++)
#pragma unroll
            for (int j = 0; j < 4; j++) acc[e][j] = 0.f;
        for (int d = 0; d < 32; d++) {
            uchar4 qu = *(const uchar4*)(&qb[(size_t)d * N_]);
            float4 qv = {(float)qu.x, (float)qu.y, (float)qu.z, (float)qu.w};
#pragma unroll
            for (int e = 0; e < 16; e++) {
                float kvv = kvs[d * 32 + eg * 16 + e];
                acc[e][0] += qv.x * kvv;
                acc[e][1] += qv.y * kvv;
                acc[e][2] += qv.z * kvv;
                acc[e][3] += qv.w * kvv;
            }
        }
#pragma unroll
        for (int e = 0; e < 16; e++) {
            float4 ov = {acc[e][0] * scale, acc[e][1] * scale,
                         acc[e][2] * scale, acc[e][3] * scale};
            *(float4*)(&ob[(size_t)(eg * 16 + e) * N_]) = ov;
        }
    }
}

// ---------------------------------------------------------------------------
extern "C" void kernel_launch(void* const* d_in, const int* in_sizes, int n_in,
                              void* d_out, int out_size, void* d_ws, size_t ws_size,
                              hipStream_t stream) {
    const float* x = (const float*)d_in[0];
    const float* q_w1 = (const float*)d_in[1];
    const float* q_dw = (const float*)d_in[2];
    const float* q_pw = (const float*)d_in[3];
    const float* q_bn = (const float*)d_in[4];
    const float* k_w1 = (const float*)d_in[5];
    const float* k_dw = (const float*)d_in[6];
    const float* k_pw = (const float*)d_in[7];
    const float* k_bn = (const float*)d_in[8];
    const float* v_w1 = (const float*)d_in[9];
    const float* v_dw = (const float*)d_in[10];
    const float* v_pw = (const float*)d_in[11];
    const float* v_bn = (const float*)d_in[12];
    const float* p_w1 = (const float*)d_in[13];
    const float* p_dw = (const float*)d_in[14];
    const float* p_pw = (const float*)d_in[15];
    const float* p_bn = (const float*)d_in[16];

    const size_t SZ = (size_t)T_ * CN_;   // 8,388,608 elements
    float* out = (float*)d_out;           // fp32 ping / bf16-pair home / final
    float* S0 = (float*)d_ws;             // fp32 pong, 33.5 MB
    float* bufKV = S0 + SZ;               // 65,536 floats
    unsigned char* xs = (unsigned char*)(bufKV + 65536);   // u8 spikes (x / o)
    unsigned char* sq = xs + SZ;                           // u8 spikes (q)
    u64* kbp = (u64*)(sq + SZ);
    u64* vbp = kbp + (SZ >> 6);
    unsigned short* wspA = (unsigned short*)(vbp + (SZ >> 6));  // 8*3*65536
    unsigned short* ST = wspA + 8 * 3 * 65536;                  // SZ shorts
    // ws total: 33.5 + 0.26 + 8.4 + 8.4 + 1.05 + 1.05 + 3.1 + 16.8 = ~72.6 MB

    dim3 gLif(CN_ / 256), bLif(256);
    dim3 gGemm(N_ / 128, C_ / 128, T_), bGemm(256);
    dim3 gDw(16, C_, T_), bDw(256);
    dim3 gTr(N_ / 32, T_), bTr(256);

    WPtrs wp;
    wp.w[0] = q_w1; wp.w[1] = q_pw; wp.w[2] = k_w1; wp.w[3] = k_pw;
    wp.w[4] = v_w1; wp.w[5] = v_pw; wp.w[6] = p_w1; wp.w[7] = p_pw;
    split_w<<<dim3(256, 8), dim3(256), 0, stream>>>(wp, wspA);
    const size_t WS3 = 3 * 65536;

    unsigned short* outH = (unsigned short*)out;
    unsigned short* outL = outH + SZ;
    unsigned short* s0H = (unsigned short*)S0;
    unsigned short* s0L = s0H + SZ;

    // xs = lif(x); spike fragments -> ST (shared by q,k,v)
    lif_u8<<<gLif, bLif, 0, stream>>>(x, xs);
    trans_s<<<gTr, bTr, 0, stream>>>(xs, ST);

    // q branch
    gemm_s2<<<gGemm, bGemm, 0, stream>>>(wspA + 0 * WS3, ST, out);
    dw_bn_pad<<<gDw, bDw, 0, stream>>>(out, q_dw, q_bn, S0);
    trans_split<<<gTr, bTr, 0, stream>>>(S0, outH, outL);
    gemm_f2<<<gGemm, bGemm, 0, stream>>>(wspA + 1 * WS3, outH, outL, S0, q_bn);
    lif_u8<<<gLif, bLif, 0, stream>>>(S0, sq);

    // k branch
    gemm_s2<<<gGemm, bGemm, 0, stream>>>(wspA + 2 * WS3, ST, out);
    dw_bn_pad<<<gDw, bDw, 0, stream>>>(out, k_dw, k_bn, S0);
    trans_split<<<gTr, bTr, 0, stream>>>(S0, outH, outL);
    gemm_f2<<<gGemm, bGemm, 0, stream>>>(wspA + 3 * WS3, outH, outL, S0, k_bn);
    lif_bp<<<gLif, bLif, 0, stream>>>(S0, kbp);

    // v branch
    gemm_s2<<<gGemm, bGemm, 0, stream>>>(wspA + 4 * WS3, ST, out);
    dw_bn_pad<<<gDw, bDw, 0, stream>>>(out, v_dw, v_bn, S0);
    trans_split<<<gTr, bTr, 0, stream>>>(S0, outH, outL);
    gemm_f2<<<gGemm, bGemm, 0, stream>>>(wspA + 5 * WS3, outH, outL, S0, v_bn);
    lif_bp<<<gLif, bLif, 0, stream>>>(S0, vbp);

    // attention (exact popcount), o = q . kv, lif -> xs, fragments -> ST
    attn_kv_bp<<<dim3(64), dim3(1024), 0, stream>>>(kbp, vbp, bufKV);
    attn_o_u8<<<dim3(4, 8, 8), dim3(256), 0, stream>>>(sq, bufKV, S0);
    lif_u8<<<gLif, bLif, 0, stream>>>(S0, xs);
    trans_s<<<gTr, bTr, 0, stream>>>(xs, ST);

    // p branch -> d_out  (bf16 pair lives in S0 this time)
    gemm_s2<<<gGemm, bGemm, 0, stream>>>(wspA + 6 * WS3, ST, S0);
    dw_bn_pad<<<gDw, bDw, 0, stream>>>(S0, p_dw, p_bn, out);
    trans_split<<<gTr, bTr, 0, stream>>>(out, s0H, s0L);
    gemm_f2<<<gGemm, bGemm, 0, stream>>>(wspA + 7 * WS3, s0H, s0L, out, p_bn);
}